// Round 1
// baseline (662.646 us; speedup 1.0000x reference)
//
#include <hip/hip_runtime.h>
#include <stdint.h>

// Problem constants
#define BQ 8
#define NXQ 512
#define WQ 16
#define DXQ 1536
#define DYQ 1024
#define DQ 768
#define HQ 12
#define PQ 8
// derived
#define MY 65536            // B*NX*W rows of y
#define BN_ROWS 4096        // B*NX

typedef __attribute__((ext_vector_type(8))) short short8;
typedef __attribute__((ext_vector_type(4))) float f32x4;
typedef unsigned short ushort_t;
typedef unsigned int uint_t;

__device__ __forceinline__ ushort_t f2bf(float f) {
  uint_t u = __float_as_uint(f);
  u += 0x7FFFu + ((u >> 16) & 1u);   // RNE
  return (ushort_t)(u >> 16);
}
__device__ __forceinline__ float bf2f(ushort_t h) {
  return __uint_as_float(((uint_t)h) << 16);
}
__device__ __forceinline__ void gload_lds16(const void* g, void* l) {
  __builtin_amdgcn_global_load_lds(
      (__attribute__((address_space(1))) unsigned int*)(g),
      (__attribute__((address_space(3))) unsigned int*)(l), 16, 0, 0);
}

// ---------------- K0: weight transpose + bf16 convert -------------------
// WyT[n][k] = Wy[k][n] (768x1024), WvT[n][k]=Wv[k][n], WoT[n][k]=Wo[k][n]
__global__ void k_conv(const float* __restrict__ Wy, const float* __restrict__ Wv,
                       const float* __restrict__ Wo, ushort_t* __restrict__ WyT,
                       ushort_t* __restrict__ WvT, ushort_t* __restrict__ WoT) {
  const int N1 = DQ * DYQ;
  const int N2 = DQ * DQ;
  const int total = N1 + 2 * N2;
  for (int i = blockIdx.x * blockDim.x + threadIdx.x; i < total;
       i += gridDim.x * blockDim.x) {
    if (i < N1) {
      int n = i / DYQ, k = i - n * DYQ;
      WyT[i] = f2bf(Wy[k * DQ + n]);
    } else if (i < N1 + N2) {
      int j = i - N1;
      int n = j / DQ, k = j - n * DQ;
      WvT[j] = f2bf(Wv[k * DQ + n]);
    } else {
      int j = i - N1 - N2;
      int n = j / DQ, k = j - n * DQ;
      WoT[j] = f2bf(Wo[k * DQ + n]);
    }
  }
}

// ---------------- q-chain (tiny) ----------------------------------------
// xp0[b,:] = l2n(x[b,0,:] @ Wx + bx)
__global__ void k_q1(const float* __restrict__ x, const float* __restrict__ Wx,
                     const float* __restrict__ bx, float* __restrict__ xp0) {
  __shared__ float red[256];
  const int b = blockIdx.x, tid = threadIdx.x;
  const float* xr = x + (size_t)b * NXQ * DXQ;  // row 0 of batch b
  float acc[3];
#pragma unroll
  for (int j = 0; j < 3; ++j) acc[j] = bx[tid + j * 256];
  for (int k = 0; k < DXQ; ++k) {
    float xv = xr[k];
#pragma unroll
    for (int j = 0; j < 3; ++j) acc[j] += xv * Wx[k * DQ + tid + j * 256];
  }
  float ssq = acc[0] * acc[0] + acc[1] * acc[1] + acc[2] * acc[2];
  red[tid] = ssq;
  __syncthreads();
  for (int s = 128; s > 0; s >>= 1) {
    if (tid < s) red[tid] += red[tid + s];
    __syncthreads();
  }
  float inv = 1.0f / (sqrtf(red[0]) + 1e-6f);
#pragma unroll
  for (int j = 0; j < 3; ++j) xp0[b * DQ + tid + j * 256] = acc[j] * inv;
}

// q[b,:] = (xp0[b,:] @ Wq + bq) * 0.125
__global__ void k_q2(const float* __restrict__ xp0, const float* __restrict__ Wq,
                     const float* __restrict__ bq, float* __restrict__ qv) {
  const int b = blockIdx.x, tid = threadIdx.x;
  const float* xr = xp0 + b * DQ;
  float acc[3];
#pragma unroll
  for (int j = 0; j < 3; ++j) acc[j] = bq[tid + j * 256];
  for (int k = 0; k < DQ; ++k) {
    float xv = xr[k];
#pragma unroll
    for (int j = 0; j < 3; ++j) acc[j] += xv * Wq[k * DQ + tid + j * 256];
  }
#pragma unroll
  for (int j = 0; j < 3; ++j) qv[b * DQ + tid + j * 256] = acc[j] * 0.125f;
}

// qk[b,h,D] = sum_j Wk[D, h*64+j] * q[b, h*64+j];  cQ[b,h] = q.bk_slice
__global__ void k_q3(const float* __restrict__ Wk, const float* __restrict__ bk,
                     const float* __restrict__ qv, float* __restrict__ qk,
                     float* __restrict__ cQ) {
  const int bh = blockIdx.x;
  const int b = bh / HQ, h = bh - b * HQ;
  const int tid = threadIdx.x;
  const float* q = qv + b * DQ + h * 64;
#pragma unroll
  for (int j = 0; j < 3; ++j) {
    int dd = tid + j * 256;
    float acc = 0.f;
    for (int j2 = 0; j2 < 64; ++j2) acc += Wk[dd * DQ + h * 64 + j2] * q[j2];
    qk[(size_t)bh * DQ + dd] = acc;
  }
  if (tid == 0) {
    float acc = 0.f;
    for (int j2 = 0; j2 < 64; ++j2) acc += q[j2] * bk[h * 64 + j2];
    cQ[bh] = acc;
  }
}

// ---------------- K1: yp = l2n(y @ Wy + by) as bf16 ---------------------
// BM=32 rows, BN=768 (full row => in-block l2norm), BK=32, 8 waves.
// Wave w owns cols [w*96, w*96+96), tile per wave 32x96 (Mfrags=2,Nfrags=6).
// LDS: sA[32 rows][4 slots of 16B] (rotated), sB[768][4 slots] (rotated).
__global__ __launch_bounds__(512) void k_gemm_yp(const float* __restrict__ y,
                                                 const ushort_t* __restrict__ WyT,
                                                 const float* __restrict__ by,
                                                 ushort_t* __restrict__ yp) {
  __shared__ __align__(16) char smem[2048 + 49152 + 128];
  float* rowsq = (float*)(smem + 2048 + 49152);
  const int tid = threadIdx.x, lane = tid & 63, wv = tid >> 6;
  const int mBase = blockIdx.x * 32;
  if (tid < 32) rowsq[tid] = 0.f;

  // fragment read offsets (slot rotation: phys_slot = (chunk + row/2) & 3)
  int aOff[2], bOff[6];
#pragma unroll
  for (int mf = 0; mf < 2; ++mf) {
    int r = mf * 16 + (lane & 15);
    int s = ((lane >> 4) + (r >> 1)) & 3;
    aOff[mf] = r * 64 + s * 16;
  }
#pragma unroll
  for (int nf = 0; nf < 6; ++nf) {
    int n = wv * 96 + nf * 16 + (lane & 15);
    int s = ((lane >> 4) + (n >> 1)) & 3;
    bOff[nf] = 2048 + n * 64 + s * 16;
  }
  // A staging (reg path, threads 0..127): phys slot as_, logical chunk ac
  const int am = tid >> 2, as_ = tid & 3;
  const int ac = (as_ - (am >> 1)) & 3;
  const float* aSrc = y + (size_t)(mBase + am) * DYQ + ac * 8;
  const int aDst = am * 64 + as_ * 16;
  // B staging via global_load_lds: per-lane source carries inverse rotation
  int bSrc[6];
#pragma unroll
  for (int i = 0; i < 6; ++i) {
    int n = (i * 8 + wv) * 16 + (lane >> 2);
    int c = ((lane & 3) - (n >> 1)) & 3;
    bSrc[i] = n * DYQ + c * 8;
  }

  f32x4 acc[2][6] = {};
  for (int t = 0; t < DYQ / 32; ++t) {
    __syncthreads();
    if (tid < 128) {
      const float4* p4 = (const float4*)(aSrc + t * 32);
      float4 f0 = p4[0], f1 = p4[1];
      short8 hv;
      hv[0] = (short)f2bf(f0.x); hv[1] = (short)f2bf(f0.y);
      hv[2] = (short)f2bf(f0.z); hv[3] = (short)f2bf(f0.w);
      hv[4] = (short)f2bf(f1.x); hv[5] = (short)f2bf(f1.y);
      hv[6] = (short)f2bf(f1.z); hv[7] = (short)f2bf(f1.w);
      *(short8*)(smem + aDst) = hv;
    }
#pragma unroll
    for (int i = 0; i < 6; ++i)
      gload_lds16(WyT + bSrc[i] + t * 32, smem + 2048 + (i * 8 + wv) * 1024);
    __syncthreads();
    short8 af[2];
#pragma unroll
    for (int mf = 0; mf < 2; ++mf) af[mf] = *(const short8*)(smem + aOff[mf]);
#pragma unroll
    for (int nf = 0; nf < 6; ++nf) {
      short8 bfv = *(const short8*)(smem + bOff[nf]);
#pragma unroll
      for (int mf = 0; mf < 2; ++mf)
        acc[mf][nf] =
            __builtin_amdgcn_mfma_f32_16x16x32_bf16(af[mf], bfv, acc[mf][nf], 0, 0, 0);
    }
  }
  // epilogue: +bias, row sumsq (cols butterfly + cross-wave LDS), scale, store
  float byv[6];
#pragma unroll
  for (int nf = 0; nf < 6; ++nf) byv[nf] = by[wv * 96 + nf * 16 + (lane & 15)];
#pragma unroll
  for (int mf = 0; mf < 2; ++mf)
#pragma unroll
    for (int r = 0; r < 4; ++r) {
      float ssq = 0.f;
#pragma unroll
      for (int nf = 0; nf < 6; ++nf) {
        float z = acc[mf][nf][r] + byv[nf];
        acc[mf][nf][r] = z;
        ssq += z * z;
      }
#pragma unroll
      for (int o = 1; o < 16; o <<= 1) ssq += __shfl_xor(ssq, o, 64);
      if ((lane & 15) == 0)
        atomicAdd(&rowsq[mf * 16 + (lane >> 4) * 4 + r], ssq);
    }
  __syncthreads();
#pragma unroll
  for (int mf = 0; mf < 2; ++mf)
#pragma unroll
    for (int r = 0; r < 4; ++r) {
      int row = mf * 16 + (lane >> 4) * 4 + r;
      float inv = 1.0f / (sqrtf(rowsq[row]) + 1e-6f);
      size_t base = (size_t)(mBase + row) * DQ;
#pragma unroll
      for (int nf = 0; nf < 6; ++nf)
        yp[base + wv * 96 + nf * 16 + (lane & 15)] = f2bf(acc[mf][nf][r] * inv);
    }
}

// ---------------- K2: windowed attention -> p[b,n,h,:] ------------------
__global__ __launch_bounds__(256) void k_attn(const ushort_t* __restrict__ yp,
                                              const float* __restrict__ qk,
                                              const float* __restrict__ cQ,
                                              ushort_t* __restrict__ p) {
  __shared__ __align__(16) char smem[16 * 1552 + 192 * 4 * 2];
  float* s_l = (float*)(smem + 16 * 1552);
  float* a_l = s_l + 192;
  const int bn = blockIdx.x, b = bn >> 9;
  const int tid = threadIdx.x;
  // stage window 16x768 bf16, rows padded to 1552B
  for (int j = tid; j < 16 * 96; j += 256) {
    int w = j / 96, ch = j - w * 96;
    *(short8*)(smem + w * 1552 + ch * 16) =
        *(const short8*)(yp + ((size_t)bn * 16 + w) * DQ + ch * 8);
  }
  __syncthreads();
  if (tid < 192) {  // (h,w) pairs: s = yp_row . qk~ + c
    int h = tid >> 4, w = tid & 15;
    const float4* qkp = (const float4*)(qk + (size_t)(b * HQ + h) * DQ);
    float acc = cQ[b * HQ + h];
    const char* yrow = smem + w * 1552;
    for (int dc = 0; dc < 192; ++dc) {
      float4 q4 = qkp[dc];
      uint2 hh = *(const uint2*)(yrow + dc * 8);
      acc += q4.x * bf2f((ushort_t)(hh.x & 0xffff));
      acc += q4.y * bf2f((ushort_t)(hh.x >> 16));
      acc += q4.z * bf2f((ushort_t)(hh.y & 0xffff));
      acc += q4.w * bf2f((ushort_t)(hh.y >> 16));
    }
    s_l[tid] = acc;
  }
  __syncthreads();
  if (tid < 12) {  // softmax over w
    float mx = -1e30f;
#pragma unroll
    for (int w = 0; w < 16; ++w) mx = fmaxf(mx, s_l[tid * 16 + w]);
    float sm = 0.f, ev[16];
#pragma unroll
    for (int w = 0; w < 16; ++w) {
      ev[w] = __expf(s_l[tid * 16 + w] - mx);
      sm += ev[w];
    }
    float inv = 1.0f / sm;
#pragma unroll
    for (int w = 0; w < 16; ++w) a_l[tid * 16 + w] = ev[w] * inv;
  }
  __syncthreads();
  // p[h,:] = sum_w a[h,w] * yp[w,:]
  for (int h = 0; h < HQ; ++h) {
    float aw[16];
#pragma unroll
    for (int w = 0; w < 16; ++w) aw[w] = a_l[h * 16 + w];
#pragma unroll
    for (int i = 0; i < 3; ++i) {
      int col = tid + i * 256;
      float acc = 0.f;
#pragma unroll
      for (int w = 0; w < 16; ++w)
        acc += aw[w] * bf2f(*(const ushort_t*)(smem + w * 1552 + col * 2));
      p[((size_t)bn * HQ + h) * DQ + col] = f2bf(acc);
    }
  }
}

// ---------------- K3: ctx[:, h*64:(h+1)*64] = p_h @ Wv_h + bv -----------
__global__ __launch_bounds__(256) void k_gemm_pv(const ushort_t* __restrict__ p,
                                                 const ushort_t* __restrict__ WvT,
                                                 const float* __restrict__ bv,
                                                 ushort_t* __restrict__ ctx) {
  __shared__ __align__(16) char smem[4096 + 4096];
  const int tid = threadIdx.x, lane = tid & 63, wv = tid >> 6;
  const int mBase = blockIdx.x * 64, h = blockIdx.y;
  int aOff, bOff[4];
  {
    int r = wv * 16 + (lane & 15);
    int s = ((lane >> 4) + (r >> 1)) & 3;
    aOff = r * 64 + s * 16;
  }
#pragma unroll
  for (int nf = 0; nf < 4; ++nf) {
    int n = nf * 16 + (lane & 15);
    int s = ((lane >> 4) + (n >> 1)) & 3;
    bOff[nf] = 4096 + n * 64 + s * 16;
  }
  const int ar = wv * 16 + (lane >> 2);
  const int ca = ((lane & 3) - (ar >> 1)) & 3;
  const ushort_t* aSrc = p + ((size_t)(mBase + ar) * HQ + h) * DQ + ca * 8;
  const ushort_t* bSrc = WvT + (size_t)(h * 64 + ar) * DQ + ca * 8;
  f32x4 acc[4] = {};
  for (int t = 0; t < DQ / 32; ++t) {
    __syncthreads();
    gload_lds16(aSrc + t * 32, smem + wv * 1024);
    gload_lds16(bSrc + t * 32, smem + 4096 + wv * 1024);
    __syncthreads();
    short8 af = *(const short8*)(smem + aOff);
#pragma unroll
    for (int nf = 0; nf < 4; ++nf) {
      short8 bfv = *(const short8*)(smem + bOff[nf]);
      acc[nf] = __builtin_amdgcn_mfma_f32_16x16x32_bf16(af, bfv, acc[nf], 0, 0, 0);
    }
  }
#pragma unroll
  for (int nf = 0; nf < 4; ++nf) {
    int col = h * 64 + nf * 16 + (lane & 15);
    float bvv = bv[col];
#pragma unroll
    for (int r = 0; r < 4; ++r) {
      int row = mBase + wv * 16 + (lane >> 4) * 4 + r;
      ctx[(size_t)row * DQ + col] = f2bf(acc[nf][r] + bvv);
    }
  }
}

// ---------------- K4: o = ctx @ Wo + bo, LayerNorm, write row 0 ---------
__global__ __launch_bounds__(512) void k_gemm_o(const ushort_t* __restrict__ ctx,
                                                const ushort_t* __restrict__ WoT,
                                                const float* __restrict__ bo,
                                                const float* __restrict__ ln_g,
                                                const float* __restrict__ ln_b,
                                                float* __restrict__ out) {
  __shared__ __align__(16) char smem[1024 + 49152 + 128];
  float* redS = (float*)(smem + 1024 + 49152);
  float* redQ = redS + 16;
  const int tid = threadIdx.x, lane = tid & 63, wv = tid >> 6;
  const int mBase = blockIdx.x * 16;
  if (tid < 16) { redS[tid] = 0.f; redQ[tid] = 0.f; }
  int aOff, bOff[6];
  {
    int r = lane & 15;
    int s = ((lane >> 4) + (r >> 1)) & 3;
    aOff = r * 64 + s * 16;
  }
#pragma unroll
  for (int nf = 0; nf < 6; ++nf) {
    int n = wv * 96 + nf * 16 + (lane & 15);
    int s = ((lane >> 4) + (n >> 1)) & 3;
    bOff[nf] = 1024 + n * 64 + s * 16;
  }
  const int ar = lane >> 2;
  const int ca = ((lane & 3) - (ar >> 1)) & 3;
  const ushort_t* aSrc = ctx + (size_t)(mBase + ar) * DQ + ca * 8;
  int bSrc[6];
#pragma unroll
  for (int i = 0; i < 6; ++i) {
    int n = (i * 8 + wv) * 16 + (lane >> 2);
    int cb = ((lane & 3) - (n >> 1)) & 3;
    bSrc[i] = n * DQ + cb * 8;
  }
  f32x4 acc[6] = {};
  for (int t = 0; t < DQ / 32; ++t) {
    __syncthreads();
    if (wv == 0) gload_lds16(aSrc + t * 32, smem);
#pragma unroll
    for (int i = 0; i < 6; ++i)
      gload_lds16(WoT + bSrc[i] + t * 32, smem + 1024 + (i * 8 + wv) * 1024);
    __syncthreads();
    short8 af = *(const short8*)(smem + aOff);
#pragma unroll
    for (int nf = 0; nf < 6; ++nf) {
      short8 bfv = *(const short8*)(smem + bOff[nf]);
      acc[nf] = __builtin_amdgcn_mfma_f32_16x16x32_bf16(af, bfv, acc[nf], 0, 0, 0);
    }
  }
  float bov[6], gv[6], bbv[6];
  int colv[6];
#pragma unroll
  for (int nf = 0; nf < 6; ++nf) {
    int col = wv * 96 + nf * 16 + (lane & 15);
    colv[nf] = col; bov[nf] = bo[col]; gv[nf] = ln_g[col]; bbv[nf] = ln_b[col];
  }
#pragma unroll
  for (int r = 0; r < 4; ++r) {
    float s1 = 0.f, s2 = 0.f;
#pragma unroll
    for (int nf = 0; nf < 6; ++nf) {
      float z = acc[nf][r] + bov[nf];
      acc[nf][r] = z;
      s1 += z;
      s2 += z * z;
    }
#pragma unroll
    for (int o = 1; o < 16; o <<= 1) {
      s1 += __shfl_xor(s1, o, 64);
      s2 += __shfl_xor(s2, o, 64);
    }
    if ((lane & 15) == 0) {
      int row = (lane >> 4) * 4 + r;
      atomicAdd(&redS[row], s1);
      atomicAdd(&redQ[row], s2);
    }
  }
  __syncthreads();
#pragma unroll
  for (int r = 0; r < 4; ++r) {
    int row = (lane >> 4) * 4 + r;
    float mu = redS[row] * (1.0f / DQ);
    float va = redQ[row] * (1.0f / DQ) - mu * mu;
    float rstd = rsqrtf(va + 1e-6f);
    int bn = mBase + row;
    int b = bn >> 9, n = bn & 511;
    size_t obase = ((size_t)b * (NXQ * (PQ + 1)) + (size_t)n * (PQ + 1)) * DQ;
#pragma unroll
    for (int nf = 0; nf < 6; ++nf)
      out[obase + colv[nf]] = (acc[nf][r] - mu) * rstd * gv[nf] + bbv[nf];
  }
}

// ---------------- K5: broadcast prompt rows -----------------------------
__global__ void k_prompt(const float* __restrict__ prompt, float* __restrict__ out) {
  const int N4 = BQ * NXQ * PQ * (DQ / 4);
  for (int j = blockIdx.x * blockDim.x + threadIdx.x; j < N4;
       j += gridDim.x * blockDim.x) {
    int d4 = j % (DQ / 4);
    int rest = j / (DQ / 4);
    int pi = rest % PQ;
    int rest2 = rest / PQ;
    int n = rest2 % NXQ;
    int b = rest2 / NXQ;
    float4 v = ((const float4*)prompt)[pi * (DQ / 4) + d4];
    ((float4*)out)[((size_t)b * (NXQ * 9) + (size_t)n * 9 + 1 + pi) * (DQ / 4) + d4] = v;
  }
}

extern "C" void kernel_launch(void* const* d_in, const int* in_sizes, int n_in,
                              void* d_out, int out_size, void* d_ws, size_t ws_size,
                              hipStream_t stream) {
  (void)in_sizes; (void)n_in; (void)out_size; (void)ws_size;
  const float* x    = (const float*)d_in[0];
  const float* y    = (const float*)d_in[1];
  const float* Wx   = (const float*)d_in[2];
  const float* bx   = (const float*)d_in[3];
  const float* Wy   = (const float*)d_in[4];
  const float* by   = (const float*)d_in[5];
  const float* prom = (const float*)d_in[6];
  const float* Wq   = (const float*)d_in[7];
  const float* bq   = (const float*)d_in[8];
  const float* Wk   = (const float*)d_in[9];
  const float* bk   = (const float*)d_in[10];
  const float* Wv   = (const float*)d_in[11];
  const float* bv   = (const float*)d_in[12];
  const float* Wo   = (const float*)d_in[13];
  const float* bo   = (const float*)d_in[14];
  const float* lng  = (const float*)d_in[15];
  const float* lnb  = (const float*)d_in[16];
  float* out = (float*)d_out;
  char* ws = (char*)d_ws;

  size_t oWyT = 0;
  size_t oWvT = oWyT + (size_t)DQ * DYQ * 2;
  size_t oWoT = oWvT + (size_t)DQ * DQ * 2;
  size_t oXp0 = oWoT + (size_t)DQ * DQ * 2;
  size_t oQ   = oXp0 + (size_t)BQ * DQ * 4;
  size_t oQK  = oQ   + (size_t)BQ * DQ * 4;
  size_t oC   = oQK  + (size_t)BQ * HQ * DQ * 4;
  size_t oYp  = oC   + 1024;
  size_t oP   = oYp  + (size_t)MY * DQ * 2;
  size_t oCtx = oP   + (size_t)BN_ROWS * HQ * DQ * 2;
  // total ~187 MB

  ushort_t* WyT = (ushort_t*)(ws + oWyT);
  ushort_t* WvT = (ushort_t*)(ws + oWvT);
  ushort_t* WoT = (ushort_t*)(ws + oWoT);
  float* xp0 = (float*)(ws + oXp0);
  float* qv  = (float*)(ws + oQ);
  float* qk  = (float*)(ws + oQK);
  float* cQ  = (float*)(ws + oC);
  ushort_t* yp  = (ushort_t*)(ws + oYp);
  ushort_t* p   = (ushort_t*)(ws + oP);
  ushort_t* ctx = (ushort_t*)(ws + oCtx);

  k_conv<<<dim3(1024), dim3(256), 0, stream>>>(Wy, Wv, Wo, WyT, WvT, WoT);
  k_q1<<<dim3(BQ), dim3(256), 0, stream>>>(x, Wx, bx, xp0);
  k_q2<<<dim3(BQ), dim3(256), 0, stream>>>(xp0, Wq, bq, qv);
  k_q3<<<dim3(BQ * HQ), dim3(256), 0, stream>>>(Wk, bk, qv, qk, cQ);
  k_gemm_yp<<<dim3(MY / 32), dim3(512), 0, stream>>>(y, WyT, by, yp);
  k_attn<<<dim3(BN_ROWS), dim3(256), 0, stream>>>(yp, qk, cQ, p);
  k_gemm_pv<<<dim3(BN_ROWS / 64, HQ), dim3(256), 0, stream>>>(p, WvT, bv, ctx);
  k_gemm_o<<<dim3(BN_ROWS / 16), dim3(512), 0, stream>>>(ctx, WoT, bo, lng, lnb, out);
  k_prompt<<<dim3(2048), dim3(256), 0, stream>>>(prom, out);
}

// Round 2
// 645.351 us; speedup vs baseline: 1.0268x; 1.0268x over previous
//
#include <hip/hip_runtime.h>
#include <stdint.h>

// Problem constants
#define BQ 8
#define NXQ 512
#define WQ 16
#define DXQ 1536
#define DYQ 1024
#define DQ 768
#define HQ 12
#define PQ 8
// derived
#define MY 65536            // B*NX*W rows of y
#define BN_ROWS 4096        // B*NX

typedef __attribute__((ext_vector_type(8))) short short8;
typedef __attribute__((ext_vector_type(4))) float f32x4;
typedef unsigned short ushort_t;
typedef unsigned int uint_t;

__device__ __forceinline__ ushort_t f2bf(float f) {
  uint_t u = __float_as_uint(f);
  u += 0x7FFFu + ((u >> 16) & 1u);   // RNE
  return (ushort_t)(u >> 16);
}
__device__ __forceinline__ float bf2f(ushort_t h) {
  return __uint_as_float(((uint_t)h) << 16);
}
__device__ __forceinline__ uint_t pkbf(float a, float b) {
  return (uint_t)f2bf(a) | ((uint_t)f2bf(b) << 16);
}
__device__ __forceinline__ void gload_lds16(const void* g, void* l) {
  __builtin_amdgcn_global_load_lds(
      (__attribute__((address_space(1))) unsigned int*)(g),
      (__attribute__((address_space(3))) unsigned int*)(l), 16, 0, 0);
}

// ---------------- K0: weight transpose + bf16 convert + rowsq zero ------
__global__ void k_conv(const float* __restrict__ Wy, const float* __restrict__ Wv,
                       const float* __restrict__ Wo, ushort_t* __restrict__ WyT,
                       ushort_t* __restrict__ WvT, ushort_t* __restrict__ WoT,
                       float* __restrict__ rowsq) {
  const int N1 = DQ * DYQ;
  const int N2 = DQ * DQ;
  const int total = N1 + 2 * N2;
  const int gstride = gridDim.x * blockDim.x;
  const int g0 = blockIdx.x * blockDim.x + threadIdx.x;
  for (int i = g0; i < MY; i += gstride) rowsq[i] = 0.f;
  for (int i = g0; i < total; i += gstride) {
    if (i < N1) {
      int n = i / DYQ, k = i - n * DYQ;
      WyT[i] = f2bf(Wy[k * DQ + n]);
    } else if (i < N1 + N2) {
      int j = i - N1;
      int n = j / DQ, k = j - n * DQ;
      WvT[j] = f2bf(Wv[k * DQ + n]);
    } else {
      int j = i - N1 - N2;
      int n = j / DQ, k = j - n * DQ;
      WoT[j] = f2bf(Wo[k * DQ + n]);
    }
  }
}

// ---------------- q-chain (tiny) ----------------------------------------
__global__ void k_q1(const float* __restrict__ x, const float* __restrict__ Wx,
                     const float* __restrict__ bx, float* __restrict__ xp0) {
  __shared__ float red[256];
  const int b = blockIdx.x, tid = threadIdx.x;
  const float* xr = x + (size_t)b * NXQ * DXQ;  // row 0 of batch b
  float acc[3];
#pragma unroll
  for (int j = 0; j < 3; ++j) acc[j] = bx[tid + j * 256];
  for (int k = 0; k < DXQ; ++k) {
    float xv = xr[k];
#pragma unroll
    for (int j = 0; j < 3; ++j) acc[j] += xv * Wx[k * DQ + tid + j * 256];
  }
  float ssq = acc[0] * acc[0] + acc[1] * acc[1] + acc[2] * acc[2];
  red[tid] = ssq;
  __syncthreads();
  for (int s = 128; s > 0; s >>= 1) {
    if (tid < s) red[tid] += red[tid + s];
    __syncthreads();
  }
  float inv = 1.0f / (sqrtf(red[0]) + 1e-6f);
#pragma unroll
  for (int j = 0; j < 3; ++j) xp0[b * DQ + tid + j * 256] = acc[j] * inv;
}

__global__ void k_q2(const float* __restrict__ xp0, const float* __restrict__ Wq,
                     const float* __restrict__ bq, float* __restrict__ qv) {
  const int b = blockIdx.x, tid = threadIdx.x;
  const float* xr = xp0 + b * DQ;
  float acc[3];
#pragma unroll
  for (int j = 0; j < 3; ++j) acc[j] = bq[tid + j * 256];
  for (int k = 0; k < DQ; ++k) {
    float xv = xr[k];
#pragma unroll
    for (int j = 0; j < 3; ++j) acc[j] += xv * Wq[k * DQ + tid + j * 256];
  }
#pragma unroll
  for (int j = 0; j < 3; ++j) qv[b * DQ + tid + j * 256] = acc[j] * 0.125f;
}

__global__ void k_q3(const float* __restrict__ Wk, const float* __restrict__ bk,
                     const float* __restrict__ qv, float* __restrict__ qk,
                     float* __restrict__ cQ) {
  const int bh = blockIdx.x;
  const int b = bh / HQ, h = bh - b * HQ;
  const int tid = threadIdx.x;
  const float* q = qv + b * DQ + h * 64;
#pragma unroll
  for (int j = 0; j < 3; ++j) {
    int dd = tid + j * 256;
    float acc = 0.f;
    for (int j2 = 0; j2 < 64; ++j2) acc += Wk[dd * DQ + h * 64 + j2] * q[j2];
    qk[(size_t)bh * DQ + dd] = acc;
  }
  if (tid == 0) {
    float acc = 0.f;
    for (int j2 = 0; j2 < 64; ++j2) acc += q[j2] * bk[h * 64 + j2];
    cQ[bh] = acc;
  }
}

// ---------------- K1: z = y @ Wy + by (bf16), rowsq = ||row||^2 ---------
// BM=256, BN=256, BK=64, 8 waves (2M x 4N), double-buffered LDS 2-phase.
// LDS per buf: A 256x64 bf16 (32KB, XOR-slot swizzled) + B same = 64KB; x2.
// A reg-staged from fp32 y with fused bf16 convert; B via global_load_lds
// with inverse swizzle on the per-lane GLOBAL source (linear LDS dest).
#define ABYTES 32768
#define BUFB 65536
__global__ __launch_bounds__(512) void k_gemm_yp(const float* __restrict__ y,
                                                 const ushort_t* __restrict__ WyT,
                                                 const float* __restrict__ by,
                                                 ushort_t* __restrict__ z,
                                                 float* __restrict__ rowsqg) {
  __shared__ __align__(16) char smem[2 * BUFB + 1024];
  float* rowsq_l = (float*)(smem + 2 * BUFB);
  const int tid = threadIdx.x, lane = tid & 63, wv = tid >> 6;
  const int wvM = wv >> 2, wvN = wv & 3;
  const int mBase = blockIdx.x * 256;
  const int nBase = blockIdx.y * 256;

  // A loads: row = wv*32 + i*4 + (lane>>4), kchunk = lane&15 (float4)
  const float* aLd = y + (size_t)(mBase + wv * 32 + (lane >> 4)) * DYQ + (lane & 15) * 4;
  // A writes (swizzled): slot = (kchunk>>1) ^ (r&7), half = kchunk&1
  int aWr[8];
#pragma unroll
  for (int i = 0; i < 8; ++i) {
    int r = wv * 32 + i * 4 + (lane >> 4);
    aWr[i] = r * 128 + ((((lane & 15) >> 1) ^ (r & 7)) * 16) + ((lane & 15) & 1) * 8;
  }
  // B gload: instr i covers rows n0..n0+7; lane l -> row n0+(l>>3), phys slot l&7,
  // source logical slot = (l&7)^(l>>3)
  const ushort_t* bLd[4];
  int bDst[4];
#pragma unroll
  for (int i = 0; i < 4; ++i) {
    int n0 = (wv * 4 + i) * 8;
    bLd[i] = WyT + (size_t)(nBase + n0 + (lane >> 3)) * DYQ + ((lane & 7) ^ (lane >> 3)) * 8;
    bDst[i] = ABYTES + n0 * 128;
  }
  // fragment read offsets: phys slot = (ks*4 + q) ^ e, q = lane>>4, e = lane&7
  const int q = lane >> 4, e = lane & 7;
  int slotOff[2];
  slotOff[0] = (q ^ e) * 16;
  slotOff[1] = ((4 | q) ^ e) * 16;
  int aRowB[8], bRowB[4];
#pragma unroll
  for (int mf = 0; mf < 8; ++mf) aRowB[mf] = (wvM * 128 + mf * 16 + (lane & 15)) * 128;
#pragma unroll
  for (int nf = 0; nf < 4; ++nf)
    bRowB[nf] = ABYTES + (wvN * 64 + nf * 16 + (lane & 15)) * 128;

  f32x4 acc[8][4] = {};
  // prologue: stage t=0 into buf0
  {
    float4 av[8];
#pragma unroll
    for (int i = 0; i < 8; ++i) av[i] = *(const float4*)(aLd + i * 4 * DYQ);
#pragma unroll
    for (int i = 0; i < 4; ++i) gload_lds16(bLd[i], smem + bDst[i]);
#pragma unroll
    for (int i = 0; i < 8; ++i) {
      uint2 u;
      u.x = pkbf(av[i].x, av[i].y);
      u.y = pkbf(av[i].z, av[i].w);
      *(uint2*)(smem + aWr[i]) = u;
    }
  }
  __syncthreads();

  for (int t = 0; t < 16; ++t) {
    char* cur = smem + (t & 1) * BUFB;
    char* nxt = smem + ((t + 1) & 1) * BUFB;
    float4 av[8];
    if (t < 15) {
      const float* aP = aLd + (t + 1) * 64;
#pragma unroll
      for (int i = 0; i < 8; ++i) av[i] = *(const float4*)(aP + i * 4 * DYQ);
#pragma unroll
      for (int i = 0; i < 4; ++i) gload_lds16(bLd[i] + (t + 1) * 64, nxt + bDst[i]);
    }
#pragma unroll
    for (int ks = 0; ks < 2; ++ks) {
      short8 af[8], bfr[4];
#pragma unroll
      for (int mf = 0; mf < 8; ++mf)
        af[mf] = *(const short8*)(cur + aRowB[mf] + slotOff[ks]);
#pragma unroll
      for (int nf = 0; nf < 4; ++nf)
        bfr[nf] = *(const short8*)(cur + bRowB[nf] + slotOff[ks]);
#pragma unroll
      for (int nf = 0; nf < 4; ++nf)
#pragma unroll
        for (int mf = 0; mf < 8; ++mf)
          acc[mf][nf] =
              __builtin_amdgcn_mfma_f32_16x16x32_bf16(af[mf], bfr[nf], acc[mf][nf], 0, 0, 0);
    }
    if (t < 15) {
#pragma unroll
      for (int i = 0; i < 8; ++i) {
        uint2 u;
        u.x = pkbf(av[i].x, av[i].y);
        u.y = pkbf(av[i].z, av[i].w);
        *(uint2*)(nxt + aWr[i]) = u;
      }
    }
    __syncthreads();
  }

  // ---- epilogue: bias, z -> LDS (as [256][256] bf16), row ssq ----
  if (tid < 256) rowsq_l[tid] = 0.f;
  float byv[4];
#pragma unroll
  for (int nf = 0; nf < 4; ++nf) byv[nf] = by[nBase + wvN * 64 + nf * 16 + (lane & 15)];
  float sqv[8][4];
#pragma unroll
  for (int mf = 0; mf < 8; ++mf) {
#pragma unroll
    for (int rr = 0; rr < 4; ++rr) {
      int row_l = wvM * 128 + mf * 16 + (lane >> 4) * 4 + rr;
      float ss = 0.f;
#pragma unroll
      for (int nf = 0; nf < 4; ++nf) {
        float zv = acc[mf][nf][rr] + byv[nf];
        acc[mf][nf][rr] = zv;
        ss += zv * zv;
        int col_l = wvN * 64 + nf * 16 + (lane & 15);
        *(ushort_t*)(smem + row_l * 512 + col_l * 2) = f2bf(zv);
      }
#pragma unroll
      for (int o = 1; o < 16; o <<= 1) ss += __shfl_xor(ss, o, 64);
      sqv[mf][rr] = ss;
    }
  }
  __syncthreads();
  if ((lane & 15) == 0) {
#pragma unroll
    for (int mf = 0; mf < 8; ++mf)
#pragma unroll
      for (int rr = 0; rr < 4; ++rr)
        atomicAdd(&rowsq_l[wvM * 128 + mf * 16 + (lane >> 4) * 4 + rr], sqv[mf][rr]);
  }
  __syncthreads();
  if (tid < 256) atomicAdd(&rowsqg[mBase + tid], rowsq_l[tid]);
  // coalesced copy-out: 2 rows per wave per iter, 512B contiguous each
#pragma unroll
  for (int it = 0; it < 16; ++it) {
    int row = it * 16 + (tid >> 5);
    int ch = tid & 31;
    uint4 v = *(const uint4*)(smem + row * 512 + ch * 16);
    *(uint4*)(z + (size_t)(mBase + row) * DQ + nBase + ch * 8) = v;
  }
}

// ---------------- K2: windowed attention -> p[b,n,h,:] ------------------
// Reads unnormalized z; applies inv_w = 1/(||z_w||+eps) folded into scores
// and attention weights.
__global__ __launch_bounds__(256) void k_attn(const ushort_t* __restrict__ z,
                                              const float* __restrict__ rowsqg,
                                              const float* __restrict__ qk,
                                              const float* __restrict__ cQ,
                                              ushort_t* __restrict__ p) {
  __shared__ __align__(16) char smem[16 * 1552 + 192 * 4 * 2 + 64];
  float* s_l = (float*)(smem + 16 * 1552);
  float* a_l = s_l + 192;
  float* inv_l = a_l + 192;
  const int bn = blockIdx.x, b = bn >> 9;
  const int tid = threadIdx.x;
  if (tid < 16) inv_l[tid] = 1.0f / (sqrtf(rowsqg[bn * 16 + tid]) + 1e-6f);
  for (int j = tid; j < 16 * 96; j += 256) {
    int w = j / 96, ch = j - w * 96;
    *(short8*)(smem + w * 1552 + ch * 16) =
        *(const short8*)(z + ((size_t)bn * 16 + w) * DQ + ch * 8);
  }
  __syncthreads();
  if (tid < 192) {  // (h,w): s = (z_w . qk~) * inv_w + cQ
    int h = tid >> 4, w = tid & 15;
    const float4* qkp = (const float4*)(qk + (size_t)(b * HQ + h) * DQ);
    float acc = 0.f;
    const char* yrow = smem + w * 1552;
    for (int dc = 0; dc < 192; ++dc) {
      float4 q4 = qkp[dc];
      uint2 hh = *(const uint2*)(yrow + dc * 8);
      acc += q4.x * bf2f((ushort_t)(hh.x & 0xffff));
      acc += q4.y * bf2f((ushort_t)(hh.x >> 16));
      acc += q4.z * bf2f((ushort_t)(hh.y & 0xffff));
      acc += q4.w * bf2f((ushort_t)(hh.y >> 16));
    }
    s_l[tid] = acc * inv_l[w] + cQ[b * HQ + h];
  }
  __syncthreads();
  if (tid < 12) {  // softmax over w; fold inv_w into weights
    float mx = -1e30f;
#pragma unroll
    for (int w = 0; w < 16; ++w) mx = fmaxf(mx, s_l[tid * 16 + w]);
    float sm = 0.f, ev[16];
#pragma unroll
    for (int w = 0; w < 16; ++w) {
      ev[w] = __expf(s_l[tid * 16 + w] - mx);
      sm += ev[w];
    }
    float rden = 1.0f / sm;
#pragma unroll
    for (int w = 0; w < 16; ++w) a_l[tid * 16 + w] = ev[w] * rden * inv_l[w];
  }
  __syncthreads();
  for (int h = 0; h < HQ; ++h) {
    float aw[16];
#pragma unroll
    for (int w = 0; w < 16; ++w) aw[w] = a_l[h * 16 + w];
#pragma unroll
    for (int i = 0; i < 3; ++i) {
      int col = tid + i * 256;
      float acc = 0.f;
#pragma unroll
      for (int w = 0; w < 16; ++w)
        acc += aw[w] * bf2f(*(const ushort_t*)(smem + w * 1552 + col * 2));
      p[((size_t)bn * HQ + h) * DQ + col] = f2bf(acc);
    }
  }
}

// ---------------- K3: ctx[:, h*64:(h+1)*64] = p_h @ Wv_h + bv -----------
__global__ __launch_bounds__(256) void k_gemm_pv(const ushort_t* __restrict__ p,
                                                 const ushort_t* __restrict__ WvT,
                                                 const float* __restrict__ bv,
                                                 ushort_t* __restrict__ ctx) {
  __shared__ __align__(16) char smem[4096 + 4096];
  const int tid = threadIdx.x, lane = tid & 63, wv = tid >> 6;
  const int mBase = blockIdx.x * 64, h = blockIdx.y;
  int aOff, bOff[4];
  {
    int r = wv * 16 + (lane & 15);
    int s = ((lane >> 4) + (r >> 1)) & 3;
    aOff = r * 64 + s * 16;
  }
#pragma unroll
  for (int nf = 0; nf < 4; ++nf) {
    int n = nf * 16 + (lane & 15);
    int s = ((lane >> 4) + (n >> 1)) & 3;
    bOff[nf] = 4096 + n * 64 + s * 16;
  }
  const int ar = wv * 16 + (lane >> 2);
  const int ca = ((lane & 3) - (ar >> 1)) & 3;
  const ushort_t* aSrc = p + ((size_t)(mBase + ar) * HQ + h) * DQ + ca * 8;
  const ushort_t* bSrc = WvT + (size_t)(h * 64 + ar) * DQ + ca * 8;
  f32x4 acc[4] = {};
  for (int t = 0; t < DQ / 32; ++t) {
    __syncthreads();
    gload_lds16(aSrc + t * 32, smem + wv * 1024);
    gload_lds16(bSrc + t * 32, smem + 4096 + wv * 1024);
    __syncthreads();
    short8 af = *(const short8*)(smem + aOff);
#pragma unroll
    for (int nf = 0; nf < 4; ++nf) {
      short8 bfv = *(const short8*)(smem + bOff[nf]);
      acc[nf] = __builtin_amdgcn_mfma_f32_16x16x32_bf16(af, bfv, acc[nf], 0, 0, 0);
    }
  }
#pragma unroll
  for (int nf = 0; nf < 4; ++nf) {
    int col = h * 64 + nf * 16 + (lane & 15);
    float bvv = bv[col];
#pragma unroll
    for (int r = 0; r < 4; ++r) {
      int row = mBase + wv * 16 + (lane >> 4) * 4 + r;
      ctx[(size_t)row * DQ + col] = f2bf(acc[nf][r] + bvv);
    }
  }
}

// ---------------- K4: o = ctx @ Wo + bo, LayerNorm, write row 0 ---------
__global__ __launch_bounds__(512) void k_gemm_o(const ushort_t* __restrict__ ctx,
                                                const ushort_t* __restrict__ WoT,
                                                const float* __restrict__ bo,
                                                const float* __restrict__ ln_g,
                                                const float* __restrict__ ln_b,
                                                float* __restrict__ out) {
  __shared__ __align__(16) char smem[1024 + 49152 + 128];
  float* redS = (float*)(smem + 1024 + 49152);
  float* redQ = redS + 16;
  const int tid = threadIdx.x, lane = tid & 63, wv = tid >> 6;
  const int mBase = blockIdx.x * 16;
  if (tid < 16) { redS[tid] = 0.f; redQ[tid] = 0.f; }
  int aOff, bOff[6];
  {
    int r = lane & 15;
    int s = ((lane >> 4) + (r >> 1)) & 3;
    aOff = r * 64 + s * 16;
  }
#pragma unroll
  for (int nf = 0; nf < 6; ++nf) {
    int n = wv * 96 + nf * 16 + (lane & 15);
    int s = ((lane >> 4) + (n >> 1)) & 3;
    bOff[nf] = 1024 + n * 64 + s * 16;
  }
  const int ar = lane >> 2;
  const int ca = ((lane & 3) - (ar >> 1)) & 3;
  const ushort_t* aSrc = ctx + (size_t)(mBase + ar) * DQ + ca * 8;
  int bSrc[6];
#pragma unroll
  for (int i = 0; i < 6; ++i) {
    int n = (i * 8 + wv) * 16 + (lane >> 2);
    int cb = ((lane & 3) - (n >> 1)) & 3;
    bSrc[i] = n * DQ + cb * 8;
  }
  f32x4 acc[6] = {};
  for (int t = 0; t < DQ / 32; ++t) {
    __syncthreads();
    if (wv == 0) gload_lds16(aSrc + t * 32, smem);
#pragma unroll
    for (int i = 0; i < 6; ++i)
      gload_lds16(WoT + bSrc[i] + t * 32, smem + 1024 + (i * 8 + wv) * 1024);
    __syncthreads();
    short8 af = *(const short8*)(smem + aOff);
#pragma unroll
    for (int nf = 0; nf < 6; ++nf) {
      short8 bfv = *(const short8*)(smem + bOff[nf]);
      acc[nf] = __builtin_amdgcn_mfma_f32_16x16x32_bf16(af, bfv, acc[nf], 0, 0, 0);
    }
  }
  float bov[6], gv[6], bbv[6];
  int colv[6];
#pragma unroll
  for (int nf = 0; nf < 6; ++nf) {
    int col = wv * 96 + nf * 16 + (lane & 15);
    colv[nf] = col; bov[nf] = bo[col]; gv[nf] = ln_g[col]; bbv[nf] = ln_b[col];
  }
#pragma unroll
  for (int r = 0; r < 4; ++r) {
    float s1 = 0.f, s2 = 0.f;
#pragma unroll
    for (int nf = 0; nf < 6; ++nf) {
      float zv = acc[nf][r] + bov[nf];
      acc[nf][r] = zv;
      s1 += zv;
      s2 += zv * zv;
    }
#pragma unroll
    for (int o = 1; o < 16; o <<= 1) {
      s1 += __shfl_xor(s1, o, 64);
      s2 += __shfl_xor(s2, o, 64);
    }
    if ((lane & 15) == 0) {
      int row = (lane >> 4) * 4 + r;
      atomicAdd(&redS[row], s1);
      atomicAdd(&redQ[row], s2);
    }
  }
  __syncthreads();
#pragma unroll
  for (int r = 0; r < 4; ++r) {
    int row = (lane >> 4) * 4 + r;
    float mu = redS[row] * (1.0f / DQ);
    float va = redQ[row] * (1.0f / DQ) - mu * mu;
    float rstd = rsqrtf(va + 1e-6f);
    int bn = mBase + row;
    int b = bn >> 9, n = bn & 511;
    size_t obase = ((size_t)b * (NXQ * (PQ + 1)) + (size_t)n * (PQ + 1)) * DQ;
#pragma unroll
    for (int nf = 0; nf < 6; ++nf)
      out[obase + colv[nf]] = (acc[nf][r] - mu) * rstd * gv[nf] + bbv[nf];
  }
}

// ---------------- K5: broadcast prompt rows -----------------------------
__global__ void k_prompt(const float* __restrict__ prompt, float* __restrict__ out) {
  const int N4 = BQ * NXQ * PQ * (DQ / 4);
  for (int j = blockIdx.x * blockDim.x + threadIdx.x; j < N4;
       j += gridDim.x * blockDim.x) {
    int d4 = j % (DQ / 4);
    int rest = j / (DQ / 4);
    int pi = rest % PQ;
    int rest2 = rest / PQ;
    int n = rest2 % NXQ;
    int b = rest2 / NXQ;
    float4 v = ((const float4*)prompt)[pi * (DQ / 4) + d4];
    ((float4*)out)[((size_t)b * (NXQ * 9) + (size_t)n * 9 + 1 + pi) * (DQ / 4) + d4] = v;
  }
}

extern "C" void kernel_launch(void* const* d_in, const int* in_sizes, int n_in,
                              void* d_out, int out_size, void* d_ws, size_t ws_size,
                              hipStream_t stream) {
  (void)in_sizes; (void)n_in; (void)out_size; (void)ws_size;
  const float* x    = (const float*)d_in[0];
  const float* y    = (const float*)d_in[1];
  const float* Wx   = (const float*)d_in[2];
  const float* bx   = (const float*)d_in[3];
  const float* Wy   = (const float*)d_in[4];
  const float* by   = (const float*)d_in[5];
  const float* prom = (const float*)d_in[6];
  const float* Wq   = (const float*)d_in[7];
  const float* bq   = (const float*)d_in[8];
  const float* Wk   = (const float*)d_in[9];
  const float* bk   = (const float*)d_in[10];
  const float* Wv   = (const float*)d_in[11];
  const float* bv   = (const float*)d_in[12];
  const float* Wo   = (const float*)d_in[13];
  const float* bo   = (const float*)d_in[14];
  const float* lng  = (const float*)d_in[15];
  const float* lnb  = (const float*)d_in[16];
  float* out = (float*)d_out;
  char* ws = (char*)d_ws;

  size_t oWyT = 0;
  size_t oWvT = oWyT + (size_t)DQ * DYQ * 2;
  size_t oWoT = oWvT + (size_t)DQ * DQ * 2;
  size_t oXp0 = oWoT + (size_t)DQ * DQ * 2;
  size_t oQ   = oXp0 + (size_t)BQ * DQ * 4;
  size_t oQK  = oQ   + (size_t)BQ * DQ * 4;
  size_t oC   = oQK  + (size_t)BQ * HQ * DQ * 4;
  size_t oZ   = oC   + 1024;
  size_t oP   = oZ   + (size_t)MY * DQ * 2;
  size_t oCtx = oP   + (size_t)BN_ROWS * HQ * DQ * 2;
  size_t oRq  = oCtx + (size_t)BN_ROWS * DQ * 2;

  ushort_t* WyT = (ushort_t*)(ws + oWyT);
  ushort_t* WvT = (ushort_t*)(ws + oWvT);
  ushort_t* WoT = (ushort_t*)(ws + oWoT);
  float* xp0 = (float*)(ws + oXp0);
  float* qv  = (float*)(ws + oQ);
  float* qk  = (float*)(ws + oQK);
  float* cQ  = (float*)(ws + oC);
  ushort_t* zbuf = (ushort_t*)(ws + oZ);
  ushort_t* p    = (ushort_t*)(ws + oP);
  ushort_t* ctx  = (ushort_t*)(ws + oCtx);
  float* rowsq   = (float*)(ws + oRq);

  k_conv<<<dim3(1024), dim3(256), 0, stream>>>(Wy, Wv, Wo, WyT, WvT, WoT, rowsq);
  k_q1<<<dim3(BQ), dim3(256), 0, stream>>>(x, Wx, bx, xp0);
  k_q2<<<dim3(BQ), dim3(256), 0, stream>>>(xp0, Wq, bq, qv);
  k_q3<<<dim3(BQ * HQ), dim3(256), 0, stream>>>(Wk, bk, qv, qk, cQ);
  k_gemm_yp<<<dim3(MY / 256, 3), dim3(512), 0, stream>>>(y, WyT, by, zbuf, rowsq);
  k_attn<<<dim3(BN_ROWS), dim3(256), 0, stream>>>(zbuf, rowsq, qk, cQ, p);
  k_gemm_pv<<<dim3(BN_ROWS / 64, HQ), dim3(256), 0, stream>>>(p, WvT, bv, ctx);
  k_gemm_o<<<dim3(BN_ROWS / 16), dim3(512), 0, stream>>>(ctx, WoT, bo, lng, lnb, out);
  k_prompt<<<dim3(2048), dim3(256), 0, stream>>>(prom, out);
}

// Round 3
// 633.565 us; speedup vs baseline: 1.0459x; 1.0186x over previous
//
#include <hip/hip_runtime.h>
#include <stdint.h>

// Problem constants
#define BQ 8
#define NXQ 512
#define WQ 16
#define DXQ 1536
#define DYQ 1024
#define DQ 768
#define HQ 12
#define PQ 8
// derived
#define MY 65536            // B*NX*W rows of y
#define BN_ROWS 4096        // B*NX

typedef __attribute__((ext_vector_type(8))) short short8;
typedef __attribute__((ext_vector_type(4))) float f32x4;
typedef unsigned short ushort_t;
typedef unsigned int uint_t;

__device__ __forceinline__ ushort_t f2bf(float f) {
  uint_t u = __float_as_uint(f);
  u += 0x7FFFu + ((u >> 16) & 1u);   // RNE
  return (ushort_t)(u >> 16);
}
__device__ __forceinline__ float bf2f(ushort_t h) {
  return __uint_as_float(((uint_t)h) << 16);
}
__device__ __forceinline__ uint_t pkbf(float a, float b) {
  return (uint_t)f2bf(a) | ((uint_t)f2bf(b) << 16);
}
__device__ __forceinline__ void gload_lds16(const void* g, void* l) {
  __builtin_amdgcn_global_load_lds(
      (__attribute__((address_space(1))) unsigned int*)(g),
      (__attribute__((address_space(3))) unsigned int*)(l), 16, 0, 0);
}

// ---------------- K0: weight transposes + zero accumulators -------------
__global__ void k_conv(const float* __restrict__ Wy, const float* __restrict__ Wv,
                       const float* __restrict__ Wo, ushort_t* __restrict__ WyT,
                       ushort_t* __restrict__ WvT, ushort_t* __restrict__ WoT,
                       float* __restrict__ rowsq, float* __restrict__ oS12) {
  const int N1 = DQ * DYQ;
  const int N2 = DQ * DQ;
  const int total = N1 + 2 * N2;
  const int gstride = gridDim.x * blockDim.x;
  const int g0 = blockIdx.x * blockDim.x + threadIdx.x;
  for (int i = g0; i < MY; i += gstride) rowsq[i] = 0.f;
  for (int i = g0; i < 2 * BN_ROWS; i += gstride) oS12[i] = 0.f;
  for (int i = g0; i < total; i += gstride) {
    if (i < N1) {
      int n = i / DYQ, k = i - n * DYQ;
      WyT[i] = f2bf(Wy[k * DQ + n]);
    } else if (i < N1 + N2) {
      int j = i - N1;
      int n = j / DQ, k = j - n * DQ;
      WvT[j] = f2bf(Wv[k * DQ + n]);
    } else {
      int j = i - N1 - N2;
      int n = j / DQ, k = j - n * DQ;
      WoT[j] = f2bf(Wo[k * DQ + n]);
    }
  }
}

// ---------------- q-chain (tiny) ----------------------------------------
__global__ void k_q1(const float* __restrict__ x, const float* __restrict__ Wx,
                     const float* __restrict__ bx, float* __restrict__ xp0) {
  __shared__ float red[256];
  const int b = blockIdx.x, tid = threadIdx.x;
  const float* xr = x + (size_t)b * NXQ * DXQ;
  float acc[3];
#pragma unroll
  for (int j = 0; j < 3; ++j) acc[j] = bx[tid + j * 256];
  for (int k = 0; k < DXQ; ++k) {
    float xv = xr[k];
#pragma unroll
    for (int j = 0; j < 3; ++j) acc[j] += xv * Wx[k * DQ + tid + j * 256];
  }
  float ssq = acc[0] * acc[0] + acc[1] * acc[1] + acc[2] * acc[2];
  red[tid] = ssq;
  __syncthreads();
  for (int s = 128; s > 0; s >>= 1) {
    if (tid < s) red[tid] += red[tid + s];
    __syncthreads();
  }
  float inv = 1.0f / (sqrtf(red[0]) + 1e-6f);
#pragma unroll
  for (int j = 0; j < 3; ++j) xp0[b * DQ + tid + j * 256] = acc[j] * inv;
}

__global__ void k_q2(const float* __restrict__ xp0, const float* __restrict__ Wq,
                     const float* __restrict__ bq, float* __restrict__ qv) {
  const int b = blockIdx.x, tid = threadIdx.x;
  const float* xr = xp0 + b * DQ;
  float acc[3];
#pragma unroll
  for (int j = 0; j < 3; ++j) acc[j] = bq[tid + j * 256];
  for (int k = 0; k < DQ; ++k) {
    float xv = xr[k];
#pragma unroll
    for (int j = 0; j < 3; ++j) acc[j] += xv * Wq[k * DQ + tid + j * 256];
  }
#pragma unroll
  for (int j = 0; j < 3; ++j) qv[b * DQ + tid + j * 256] = acc[j] * 0.125f;
}

__global__ void k_q3(const float* __restrict__ Wk, const float* __restrict__ bk,
                     const float* __restrict__ qv, float* __restrict__ qk,
                     float* __restrict__ cQ) {
  const int bh = blockIdx.x;
  const int b = bh / HQ, h = bh - b * HQ;
  const int tid = threadIdx.x;
  const float* q = qv + b * DQ + h * 64;
#pragma unroll
  for (int j = 0; j < 3; ++j) {
    int dd = tid + j * 256;
    float acc = 0.f;
    for (int j2 = 0; j2 < 64; ++j2) acc += Wk[dd * DQ + h * 64 + j2] * q[j2];
    qk[(size_t)bh * DQ + dd] = acc;
  }
  if (tid == 0) {
    float acc = 0.f;
    for (int j2 = 0; j2 < 64; ++j2) acc += q[j2] * bk[h * 64 + j2];
    cQ[bh] = acc;
  }
}

// ---------------- K1: z = y @ Wy + by (bf16), rowsq += ||rowpart||^2 ----
// 128x128 tile, BK=32, 4 waves (2Mx2N), dbuf. A: fp32 reg-staged ->
// bf16 into 80B-padded rows (conflict-free). B: gload_lds, 64B rows,
// XOR slot swizzle q^(r&3) applied on the global source address.
#define YP_BOFFS 10240          // A region bytes (128 rows * 80B)
#define YP_BUF 18432            // + B 128*64
__global__ __launch_bounds__(256, 3) void k_gemm_yp(const float* __restrict__ y,
                                                    const ushort_t* __restrict__ WyT,
                                                    const float* __restrict__ by,
                                                    ushort_t* __restrict__ z,
                                                    float* __restrict__ rowsqg) {
  __shared__ __align__(16) char smem[2 * YP_BUF + 512];
  float* rowsq_l = (float*)(smem + 2 * YP_BUF);
  const int tid = threadIdx.x, lane = tid & 63, wv = tid >> 6;
  const int wvM = wv >> 1, wvN = wv & 1;
  // block decode: panel-major with 8-panel groups so all 6 N-blocks of a
  // panel share g mod 8 (-> same XCD L2 caches the y panel).
  const int g = blockIdx.x;
  const int m = (g / 48) * 8 + (g & 7);
  const int n = (g >> 3) % 6;
  const int mBase = m * 128, nBase = n * 128;

  // A staging: thread -> row (tid&127), k-half (tid>>7) of the 32-k tile
  const int sRow = tid & 127, sHalf = tid >> 7;
  const float* aG = y + (size_t)(mBase + sRow) * DYQ + sHalf * 16;
  const int aOffW = sRow * 80 + sHalf * 32;
  // B staging: 8 gload instrs (2/wave), instr ii covers 16 rows of 64B
  const int ii0 = wv * 2;
  const ushort_t* bG[2];
#pragma unroll
  for (int j = 0; j < 2; ++j) {
    int r = (ii0 + j) * 16 + (lane >> 2);
    bG[j] = WyT + (size_t)(nBase + r) * DYQ + (((lane & 3) ^ ((lane >> 2) & 3)) * 8);
  }
  // fragment read offsets
  const int q = lane >> 4;
  int aFr[4], bFr[4];
#pragma unroll
  for (int mf = 0; mf < 4; ++mf)
    aFr[mf] = (wvM * 64 + mf * 16 + (lane & 15)) * 80 + q * 16;
#pragma unroll
  for (int nf = 0; nf < 4; ++nf) {
    int r = wvN * 64 + nf * 16 + (lane & 15);
    bFr[nf] = YP_BOFFS + r * 64 + ((q ^ (r & 3)) * 16);
  }

  f32x4 acc[4][4] = {};
  // prologue: stage t=0 into buf0
  {
    float4 a0 = *(const float4*)(aG), a1 = *(const float4*)(aG + 4);
    float4 a2 = *(const float4*)(aG + 8), a3 = *(const float4*)(aG + 12);
#pragma unroll
    for (int j = 0; j < 2; ++j)
      gload_lds16(bG[j], smem + YP_BOFFS + (ii0 + j) * 1024);
    uint4 w0, w1;
    w0.x = pkbf(a0.x, a0.y); w0.y = pkbf(a0.z, a0.w);
    w0.z = pkbf(a1.x, a1.y); w0.w = pkbf(a1.z, a1.w);
    w1.x = pkbf(a2.x, a2.y); w1.y = pkbf(a2.z, a2.w);
    w1.z = pkbf(a3.x, a3.y); w1.w = pkbf(a3.z, a3.w);
    *(uint4*)(smem + aOffW) = w0;
    *(uint4*)(smem + aOffW + 16) = w1;
  }
  __syncthreads();

  for (int t = 0; t < 32; ++t) {
    char* cur = smem + (t & 1) * YP_BUF;
    char* nxt = smem + ((t + 1) & 1) * YP_BUF;
    float4 a0, a1, a2, a3;
    if (t < 31) {
      const float* aP = aG + (t + 1) * 32;
      a0 = *(const float4*)(aP); a1 = *(const float4*)(aP + 4);
      a2 = *(const float4*)(aP + 8); a3 = *(const float4*)(aP + 12);
#pragma unroll
      for (int j = 0; j < 2; ++j)
        gload_lds16(bG[j] + (t + 1) * 32, nxt + YP_BOFFS + (ii0 + j) * 1024);
    }
    short8 af[4], bf[4];
#pragma unroll
    for (int mf = 0; mf < 4; ++mf) af[mf] = *(const short8*)(cur + aFr[mf]);
#pragma unroll
    for (int nf = 0; nf < 4; ++nf) bf[nf] = *(const short8*)(cur + bFr[nf]);
#pragma unroll
    for (int nf = 0; nf < 4; ++nf)
#pragma unroll
      for (int mf = 0; mf < 4; ++mf)
        acc[mf][nf] =
            __builtin_amdgcn_mfma_f32_16x16x32_bf16(af[mf], bf[nf], acc[mf][nf], 0, 0, 0);
    if (t < 31) {
      uint4 w0, w1;
      w0.x = pkbf(a0.x, a0.y); w0.y = pkbf(a0.z, a0.w);
      w0.z = pkbf(a1.x, a1.y); w0.w = pkbf(a1.z, a1.w);
      w1.x = pkbf(a2.x, a2.y); w1.y = pkbf(a2.z, a2.w);
      w1.z = pkbf(a3.x, a3.y); w1.w = pkbf(a3.z, a3.w);
      *(uint4*)(nxt + aOffW) = w0;
      *(uint4*)(nxt + aOffW + 16) = w1;
    }
    __syncthreads();
  }

  // ---- epilogue: +bias, z tile -> LDS, row ssq partials ----
  if (tid < 128) rowsq_l[tid] = 0.f;
  __syncthreads();
  float byv[4];
#pragma unroll
  for (int nf = 0; nf < 4; ++nf) byv[nf] = by[nBase + wvN * 64 + nf * 16 + (lane & 15)];
#pragma unroll
  for (int mf = 0; mf < 4; ++mf) {
#pragma unroll
    for (int rr = 0; rr < 4; ++rr) {
      int row_l = wvM * 64 + mf * 16 + (lane >> 4) * 4 + rr;
      float ss = 0.f;
#pragma unroll
      for (int nf = 0; nf < 4; ++nf) {
        float zv = acc[mf][nf][rr] + byv[nf];
        ss += zv * zv;
        int col_l = wvN * 64 + nf * 16 + (lane & 15);
        *(ushort_t*)(smem + row_l * 256 + col_l * 2) = f2bf(zv);
      }
#pragma unroll
      for (int o = 1; o < 16; o <<= 1) ss += __shfl_xor(ss, o, 64);
      if ((lane & 15) == 0) atomicAdd(&rowsq_l[row_l], ss);
    }
  }
  __syncthreads();
  if (tid < 128) atomicAdd(&rowsqg[mBase + tid], rowsq_l[tid]);
#pragma unroll
  for (int it = 0; it < 8; ++it) {
    int row = it * 16 + (tid >> 4);
    int ch = tid & 15;
    uint4 v = *(const uint4*)(smem + row * 256 + ch * 16);
    *(uint4*)(z + (size_t)(mBase + row) * DQ + nBase + ch * 8) = v;
  }
}

// ---------------- K2: windowed attention -> p[b,n,h,:] ------------------
__global__ __launch_bounds__(256) void k_attn(const ushort_t* __restrict__ z,
                                              const float* __restrict__ rowsqg,
                                              const float* __restrict__ qk,
                                              const float* __restrict__ cQ,
                                              ushort_t* __restrict__ p) {
  __shared__ __align__(16) char smem[16 * 1552 + 192 * 4 * 2 + 64];
  float* s_l = (float*)(smem + 16 * 1552);
  float* a_l = s_l + 192;
  float* inv_l = a_l + 192;
  const int bn = blockIdx.x, b = bn >> 9;
  const int tid = threadIdx.x;
  if (tid < 16) inv_l[tid] = 1.0f / (sqrtf(rowsqg[bn * 16 + tid]) + 1e-6f);
  for (int j = tid; j < 16 * 96; j += 256) {
    int w = j / 96, ch = j - w * 96;
    *(short8*)(smem + w * 1552 + ch * 16) =
        *(const short8*)(z + ((size_t)bn * 16 + w) * DQ + ch * 8);
  }
  __syncthreads();
  if (tid < 192) {  // (h,w): s = (z_w . qk~) * inv_w + cQ
    int h = tid >> 4, w = tid & 15;
    const float4* qkp = (const float4*)(qk + (size_t)(b * HQ + h) * DQ);
    float acc = 0.f;
    const char* yrow = smem + w * 1552;
    for (int dc = 0; dc < 192; ++dc) {
      float4 q4 = qkp[dc];
      uint2 hh = *(const uint2*)(yrow + dc * 8);
      acc += q4.x * bf2f((ushort_t)(hh.x & 0xffff));
      acc += q4.y * bf2f((ushort_t)(hh.x >> 16));
      acc += q4.z * bf2f((ushort_t)(hh.y & 0xffff));
      acc += q4.w * bf2f((ushort_t)(hh.y >> 16));
    }
    s_l[tid] = acc * inv_l[w] + cQ[b * HQ + h];
  }
  __syncthreads();
  if (tid < 12) {  // softmax over w; fold inv_w into weights
    float mx = -1e30f;
#pragma unroll
    for (int w = 0; w < 16; ++w) mx = fmaxf(mx, s_l[tid * 16 + w]);
    float sm = 0.f, ev[16];
#pragma unroll
    for (int w = 0; w < 16; ++w) {
      ev[w] = __expf(s_l[tid * 16 + w] - mx);
      sm += ev[w];
    }
    float rden = 1.0f / sm;
#pragma unroll
    for (int w = 0; w < 16; ++w) a_l[tid * 16 + w] = ev[w] * rden * inv_l[w];
  }
  __syncthreads();
  // PV with register-cached z columns (3 cols/thread)
  float zr[16][3];
#pragma unroll
  for (int w = 0; w < 16; ++w)
#pragma unroll
    for (int i = 0; i < 3; ++i)
      zr[w][i] = bf2f(*(const ushort_t*)(smem + w * 1552 + (tid + i * 256) * 2));
  for (int h = 0; h < HQ; ++h) {
    float acc0 = 0.f, acc1 = 0.f, acc2 = 0.f;
#pragma unroll
    for (int w = 0; w < 16; ++w) {
      float aw = a_l[h * 16 + w];
      acc0 += aw * zr[w][0];
      acc1 += aw * zr[w][1];
      acc2 += aw * zr[w][2];
    }
    size_t base = ((size_t)bn * HQ + h) * DQ + tid;
    p[base] = f2bf(acc0);
    p[base + 256] = f2bf(acc1);
    p[base + 512] = f2bf(acc2);
  }
}

// ---------------- shared 64x64 GEMM pattern (pv / o) --------------------
// 4 waves (2Mx2N), wave tile 32x32, BK=64 (2 ks), dbuf 2x16KB.
// Both A and B via gload_lds, 128B rows, XOR slot swizzle s = c ^ (r&7).

// K3: ctx[:, h*64:(h+1)*64] = p_h @ Wv_h + bv
__global__ __launch_bounds__(256) void k_gemm_pv(const ushort_t* __restrict__ p,
                                                 const ushort_t* __restrict__ WvT,
                                                 const float* __restrict__ bv,
                                                 ushort_t* __restrict__ ctx) {
  __shared__ __align__(16) char smem[2 * 16384];
  const int tid = threadIdx.x, lane = tid & 63, wv = tid >> 6;
  const int wvM = wv >> 1, wvN = wv & 1;
  const int mBase = blockIdx.x * 64, h = blockIdx.y;
  const int ii0 = wv * 2;
  const ushort_t* aG[2];
  const ushort_t* bG[2];
#pragma unroll
  for (int j = 0; j < 2; ++j) {
    int r = (ii0 + j) * 8 + (lane >> 3);
    int sc = ((lane & 7) ^ (lane >> 3)) * 8;
    aG[j] = p + ((size_t)(mBase + r) * HQ + h) * DQ + sc;
    bG[j] = WvT + (size_t)(h * 64 + r) * DQ + sc;
  }
  const int q = lane >> 4;
  int aFr[2], bFr[2];
#pragma unroll
  for (int f = 0; f < 2; ++f) {
    int ra = wvM * 32 + f * 16 + (lane & 15);
    int rb = wvN * 32 + f * 16 + (lane & 15);
    aFr[f] = ra * 128;
    bFr[f] = 8192 + rb * 128;
  }
  const int ra7 = (lane & 7), rb7 = (lane & 7);  // r&7 of frag rows
  f32x4 acc[2][2] = {};
  // prologue
#pragma unroll
  for (int j = 0; j < 2; ++j) {
    gload_lds16(aG[j], smem + (ii0 + j) * 1024);
    gload_lds16(bG[j], smem + 8192 + (ii0 + j) * 1024);
  }
  __syncthreads();
  for (int t = 0; t < 12; ++t) {
    char* cur = smem + (t & 1) * 16384;
    char* nxt = smem + ((t + 1) & 1) * 16384;
    if (t < 11) {
#pragma unroll
      for (int j = 0; j < 2; ++j) {
        gload_lds16(aG[j] + (t + 1) * 64, nxt + (ii0 + j) * 1024);
        gload_lds16(bG[j] + (t + 1) * 64, nxt + 8192 + (ii0 + j) * 1024);
      }
    }
#pragma unroll
    for (int ks = 0; ks < 2; ++ks) {
      short8 af[2], bf[2];
#pragma unroll
      for (int f = 0; f < 2; ++f) {
        af[f] = *(const short8*)(cur + aFr[f] + (((ks * 4 + q) ^ ra7) * 16));
        bf[f] = *(const short8*)(cur + bFr[f] + (((ks * 4 + q) ^ rb7) * 16));
      }
#pragma unroll
      for (int nf = 0; nf < 2; ++nf)
#pragma unroll
        for (int mf = 0; mf < 2; ++mf)
          acc[mf][nf] =
              __builtin_amdgcn_mfma_f32_16x16x32_bf16(af[mf], bf[nf], acc[mf][nf], 0, 0, 0);
    }
    __syncthreads();
  }
#pragma unroll
  for (int nf = 0; nf < 2; ++nf) {
    int col = h * 64 + wvN * 32 + nf * 16 + (lane & 15);
    float bvv = bv[col];
#pragma unroll
    for (int mf = 0; mf < 2; ++mf)
#pragma unroll
      for (int rr = 0; rr < 4; ++rr) {
        int row = mBase + wvM * 32 + mf * 16 + (lane >> 4) * 4 + rr;
        ctx[(size_t)row * DQ + col] = f2bf(acc[mf][nf][rr] + bvv);
      }
  }
}

// K4: o = ctx @ Wo + bo (fp32 to ws) + row s1/s2 global atomics
__global__ __launch_bounds__(256) void k_gemm_o(const ushort_t* __restrict__ ctx,
                                                const ushort_t* __restrict__ WoT,
                                                const float* __restrict__ bo,
                                                float* __restrict__ o,
                                                float* __restrict__ oS12) {
  __shared__ __align__(16) char smem[2 * 16384];
  const int tid = threadIdx.x, lane = tid & 63, wv = tid >> 6;
  const int wvM = wv >> 1, wvN = wv & 1;
  const int mBase = blockIdx.x * 64, nBase = blockIdx.y * 64;
  const int ii0 = wv * 2;
  const ushort_t* aG[2];
  const ushort_t* bG[2];
#pragma unroll
  for (int j = 0; j < 2; ++j) {
    int r = (ii0 + j) * 8 + (lane >> 3);
    int sc = ((lane & 7) ^ (lane >> 3)) * 8;
    aG[j] = ctx + (size_t)(mBase + r) * DQ + sc;
    bG[j] = WoT + (size_t)(nBase + r) * DQ + sc;
  }
  const int q = lane >> 4;
  int aFr[2], bFr[2];
#pragma unroll
  for (int f = 0; f < 2; ++f) {
    aFr[f] = (wvM * 32 + f * 16 + (lane & 15)) * 128;
    bFr[f] = 8192 + (wvN * 32 + f * 16 + (lane & 15)) * 128;
  }
  const int r7 = lane & 7;
  f32x4 acc[2][2] = {};
#pragma unroll
  for (int j = 0; j < 2; ++j) {
    gload_lds16(aG[j], smem + (ii0 + j) * 1024);
    gload_lds16(bG[j], smem + 8192 + (ii0 + j) * 1024);
  }
  __syncthreads();
  for (int t = 0; t < 12; ++t) {
    char* cur = smem + (t & 1) * 16384;
    char* nxt = smem + ((t + 1) & 1) * 16384;
    if (t < 11) {
#pragma unroll
      for (int j = 0; j < 2; ++j) {
        gload_lds16(aG[j] + (t + 1) * 64, nxt + (ii0 + j) * 1024);
        gload_lds16(bG[j] + (t + 1) * 64, nxt + 8192 + (ii0 + j) * 1024);
      }
    }
#pragma unroll
    for (int ks = 0; ks < 2; ++ks) {
      short8 af[2], bf[2];
#pragma unroll
      for (int f = 0; f < 2; ++f) {
        af[f] = *(const short8*)(cur + aFr[f] + (((ks * 4 + q) ^ r7) * 16));
        bf[f] = *(const short8*)(cur + bFr[f] + (((ks * 4 + q) ^ r7) * 16));
      }
#pragma unroll
      for (int nf = 0; nf < 2; ++nf)
#pragma unroll
        for (int mf = 0; mf < 2; ++mf)
          acc[mf][nf] =
              __builtin_amdgcn_mfma_f32_16x16x32_bf16(af[mf], bf[nf], acc[mf][nf], 0, 0, 0);
    }
    __syncthreads();
  }
  float bo0 = bo[nBase + wvN * 32 + (lane & 15)];
  float bo1 = bo[nBase + wvN * 32 + 16 + (lane & 15)];
#pragma unroll
  for (int mf = 0; mf < 2; ++mf)
#pragma unroll
    for (int rr = 0; rr < 4; ++rr) {
      int row = mBase + wvM * 32 + mf * 16 + (lane >> 4) * 4 + rr;
      float z0 = acc[mf][0][rr] + bo0;
      float z1 = acc[mf][1][rr] + bo1;
      o[(size_t)row * DQ + nBase + wvN * 32 + (lane & 15)] = z0;
      o[(size_t)row * DQ + nBase + wvN * 32 + 16 + (lane & 15)] = z1;
      float s1 = z0 + z1, s2 = z0 * z0 + z1 * z1;
#pragma unroll
      for (int ofs = 1; ofs < 16; ofs <<= 1) {
        s1 += __shfl_xor(s1, ofs, 64);
        s2 += __shfl_xor(s2, ofs, 64);
      }
      if ((lane & 15) == 0) {
        atomicAdd(&oS12[row], s1);
        atomicAdd(&oS12[BN_ROWS + row], s2);
      }
    }
}

// K5: LayerNorm finalize -> out row positions
__global__ __launch_bounds__(256) void k_final(const float* __restrict__ o,
                                               const float* __restrict__ oS12,
                                               const float* __restrict__ ln_g,
                                               const float* __restrict__ ln_b,
                                               float* __restrict__ out) {
  const int tid = threadIdx.x;
  const int row = blockIdx.x * 8 + (tid >> 5);
  const int l32 = tid & 31;
  float mu = oS12[row] * (1.0f / DQ);
  float va = oS12[BN_ROWS + row] * (1.0f / DQ) - mu * mu;
  float rstd = rsqrtf(va + 1e-6f);
  int b = row >> 9, n = row & 511;
  size_t obase = ((size_t)b * (NXQ * (PQ + 1)) + (size_t)n * (PQ + 1)) * DQ;
#pragma unroll
  for (int j = 0; j < 6; ++j) {
    int c4 = l32 + j * 32;
    float4 v = ((const float4*)(o + (size_t)row * DQ))[c4];
    float4 g = ((const float4*)ln_g)[c4];
    float4 bb = ((const float4*)ln_b)[c4];
    float4 r;
    r.x = (v.x - mu) * rstd * g.x + bb.x;
    r.y = (v.y - mu) * rstd * g.y + bb.y;
    r.z = (v.z - mu) * rstd * g.z + bb.z;
    r.w = (v.w - mu) * rstd * g.w + bb.w;
    ((float4*)(out + obase))[c4] = r;
  }
}

// K6: broadcast prompt rows
__global__ void k_prompt(const float* __restrict__ prompt, float* __restrict__ out) {
  const int N4 = BQ * NXQ * PQ * (DQ / 4);
  for (int j = blockIdx.x * blockDim.x + threadIdx.x; j < N4;
       j += gridDim.x * blockDim.x) {
    int d4 = j % (DQ / 4);
    int rest = j / (DQ / 4);
    int pi = rest % PQ;
    int rest2 = rest / PQ;
    int n = rest2 % NXQ;
    int b = rest2 / NXQ;
    float4 v = ((const float4*)prompt)[pi * (DQ / 4) + d4];
    ((float4*)out)[((size_t)b * (NXQ * 9) + (size_t)n * 9 + 1 + pi) * (DQ / 4) + d4] = v;
  }
}

extern "C" void kernel_launch(void* const* d_in, const int* in_sizes, int n_in,
                              void* d_out, int out_size, void* d_ws, size_t ws_size,
                              hipStream_t stream) {
  (void)in_sizes; (void)n_in; (void)out_size; (void)ws_size;
  const float* x    = (const float*)d_in[0];
  const float* y    = (const float*)d_in[1];
  const float* Wx   = (const float*)d_in[2];
  const float* bx   = (const float*)d_in[3];
  const float* Wy   = (const float*)d_in[4];
  const float* by   = (const float*)d_in[5];
  const float* prom = (const float*)d_in[6];
  const float* Wq   = (const float*)d_in[7];
  const float* bq   = (const float*)d_in[8];
  const float* Wk   = (const float*)d_in[9];
  const float* bk   = (const float*)d_in[10];
  const float* Wv   = (const float*)d_in[11];
  const float* bv   = (const float*)d_in[12];
  const float* Wo   = (const float*)d_in[13];
  const float* bo   = (const float*)d_in[14];
  const float* lng  = (const float*)d_in[15];
  const float* lnb  = (const float*)d_in[16];
  float* out = (float*)d_out;
  char* ws = (char*)d_ws;

  size_t oWyT = 0;
  size_t oWvT = oWyT + (size_t)DQ * DYQ * 2;
  size_t oWoT = oWvT + (size_t)DQ * DQ * 2;
  size_t oXp0 = oWoT + (size_t)DQ * DQ * 2;
  size_t oQ   = oXp0 + (size_t)BQ * DQ * 4;
  size_t oQK  = oQ   + (size_t)BQ * DQ * 4;
  size_t oC   = oQK  + (size_t)BQ * HQ * DQ * 4;
  size_t oZ   = oC   + 1024;                         // z (bf16), later o (fp32)
  size_t oP   = oZ   + (size_t)MY * DQ * 2;
  size_t oCtx = oP   + (size_t)BN_ROWS * HQ * DQ * 2;
  size_t oRq  = oCtx + (size_t)BN_ROWS * DQ * 2;
  size_t oS   = oRq  + (size_t)MY * 4;

  ushort_t* WyT = (ushort_t*)(ws + oWyT);
  ushort_t* WvT = (ushort_t*)(ws + oWvT);
  ushort_t* WoT = (ushort_t*)(ws + oWoT);
  float* xp0 = (float*)(ws + oXp0);
  float* qv  = (float*)(ws + oQ);
  float* qk  = (float*)(ws + oQK);
  float* cQ  = (float*)(ws + oC);
  ushort_t* zbuf = (ushort_t*)(ws + oZ);
  float* obuf    = (float*)(ws + oZ);   // aliases z (z is dead after k_attn)
  ushort_t* p    = (ushort_t*)(ws + oP);
  ushort_t* ctx  = (ushort_t*)(ws + oCtx);
  float* rowsq   = (float*)(ws + oRq);
  float* oS12    = (float*)(ws + oS);

  k_conv<<<dim3(1024), dim3(256), 0, stream>>>(Wy, Wv, Wo, WyT, WvT, WoT, rowsq, oS12);
  k_q1<<<dim3(BQ), dim3(256), 0, stream>>>(x, Wx, bx, xp0);
  k_q2<<<dim3(BQ), dim3(256), 0, stream>>>(xp0, Wq, bq, qv);
  k_q3<<<dim3(BQ * HQ), dim3(256), 0, stream>>>(Wk, bk, qv, qk, cQ);
  k_gemm_yp<<<dim3(3072), dim3(256), 0, stream>>>(y, WyT, by, zbuf, rowsq);
  k_attn<<<dim3(BN_ROWS), dim3(256), 0, stream>>>(zbuf, rowsq, qk, cQ, p);
  k_gemm_pv<<<dim3(BN_ROWS / 64, HQ), dim3(256), 0, stream>>>(p, WvT, bv, ctx);
  k_gemm_o<<<dim3(BN_ROWS / 64, DQ / 64), dim3(256), 0, stream>>>(ctx, WoT, bo, obuf, oS12);
  k_final<<<dim3(BN_ROWS / 8), dim3(256), 0, stream>>>(obuf, oS12, lng, lnb, out);
  k_prompt<<<dim3(2048), dim3(256), 0, stream>>>(prom, out);
}

// Round 4
// 554.904 us; speedup vs baseline: 1.1942x; 1.1418x over previous
//
#include <hip/hip_runtime.h>
#include <stdint.h>

// Problem constants
#define BQ 8
#define NXQ 512
#define WQ 16
#define DXQ 1536
#define DYQ 1024
#define DQ 768
#define HQ 12
#define PQ 8
// derived
#define MY 65536            // B*NX*W rows of y
#define BN_ROWS 4096        // B*NX

typedef __attribute__((ext_vector_type(8))) short short8;
typedef __attribute__((ext_vector_type(4))) float f32x4;
typedef unsigned short ushort_t;
typedef unsigned int uint_t;

__device__ __forceinline__ ushort_t f2bf(float f) {
  uint_t u = __float_as_uint(f);
  u += 0x7FFFu + ((u >> 16) & 1u);   // RNE
  return (ushort_t)(u >> 16);
}
__device__ __forceinline__ float bf2f(ushort_t h) {
  return __uint_as_float(((uint_t)h) << 16);
}
__device__ __forceinline__ void gload_lds16(const void* g, void* l) {
  __builtin_amdgcn_global_load_lds(
      (__attribute__((address_space(1))) unsigned int*)(g),
      (__attribute__((address_space(3))) unsigned int*)(l), 16, 0, 0);
}

// ---------------- K0: y->bf16, weight transposes, zero accumulators -----
__global__ void k_conv(const float* __restrict__ y, const float* __restrict__ Wy,
                       const float* __restrict__ Wv, const float* __restrict__ Wo,
                       ushort_t* __restrict__ ybf, ushort_t* __restrict__ WyT,
                       ushort_t* __restrict__ WvT, ushort_t* __restrict__ WoT,
                       float* __restrict__ rowsq, float* __restrict__ oS12,
                       float* __restrict__ xss) {
  const int gstride = gridDim.x * blockDim.x;
  const int g0 = blockIdx.x * blockDim.x + threadIdx.x;
  // y fp32 -> bf16 (67.1M elems, 8 per thread-iter)
  const int NY8 = MY * DYQ / 8;
  for (int i = g0; i < NY8; i += gstride) {
    const float4* s = (const float4*)(y + (size_t)i * 8);
    float4 f0 = s[0], f1 = s[1];
    short8 hv;
    hv[0] = (short)f2bf(f0.x); hv[1] = (short)f2bf(f0.y);
    hv[2] = (short)f2bf(f0.z); hv[3] = (short)f2bf(f0.w);
    hv[4] = (short)f2bf(f1.x); hv[5] = (short)f2bf(f1.y);
    hv[6] = (short)f2bf(f1.z); hv[7] = (short)f2bf(f1.w);
    *(short8*)(ybf + (size_t)i * 8) = hv;
  }
  // zeros
  for (int i = g0; i < MY; i += gstride) rowsq[i] = 0.f;
  for (int i = g0; i < 2 * BN_ROWS; i += gstride) oS12[i] = 0.f;
  if (g0 < BQ) xss[g0] = 0.f;
  // weight transposes (bf16)
  const int N1 = DQ * DYQ;
  const int N2 = DQ * DQ;
  const int total = N1 + 2 * N2;
  for (int i = g0; i < total; i += gstride) {
    if (i < N1) {
      int n = i / DYQ, k = i - n * DYQ;
      WyT[i] = f2bf(Wy[k * DQ + n]);
    } else if (i < N1 + N2) {
      int j = i - N1;
      int n = j / DQ, k = j - n * DQ;
      WvT[j] = f2bf(Wv[k * DQ + n]);
    } else {
      int j = i - N1 - N2;
      int n = j / DQ, k = j - n * DQ;
      WoT[j] = f2bf(Wo[k * DQ + n]);
    }
  }
}

// ---------------- q-chain (parallelized) --------------------------------
// K_q1: xw[b,c] = x[b,0,:] @ Wx[:,c] + bx[c];  xss[b] += sum_c xw^2
__global__ __launch_bounds__(128) void k_q1(const float* __restrict__ x,
                                            const float* __restrict__ Wx,
                                            const float* __restrict__ bx,
                                            float* __restrict__ xw,
                                            float* __restrict__ xss) {
  __shared__ float r2[2];
  const int b = blockIdx.x, c = blockIdx.y * 128 + threadIdx.x;
  const int t = threadIdx.x;
  const float* xr = x + (size_t)b * NXQ * DXQ;  // row 0 of batch b
  float acc = bx[c];
  for (int k = 0; k < DXQ; ++k) acc += xr[k] * Wx[(size_t)k * DQ + c];
  xw[b * DQ + c] = acc;
  float ss = acc * acc;
#pragma unroll
  for (int o = 1; o < 64; o <<= 1) ss += __shfl_xor(ss, o, 64);
  if ((t & 63) == 0) r2[t >> 6] = ss;
  __syncthreads();
  if (t == 0) atomicAdd(&xss[b], r2[0] + r2[1]);
}

// K_q2: q[b,c] = ((xw[b,:]*inv_b) @ Wq[:,c] + bq[c]) * 0.125
__global__ __launch_bounds__(128) void k_q2(const float* __restrict__ xw,
                                            const float* __restrict__ xss,
                                            const float* __restrict__ Wq,
                                            const float* __restrict__ bq,
                                            float* __restrict__ qv) {
  const int b = blockIdx.x, c = blockIdx.y * 128 + threadIdx.x;
  const float inv = 1.0f / (sqrtf(xss[b]) + 1e-6f);
  const float* xr = xw + b * DQ;
  float acc = 0.f;
  for (int k = 0; k < DQ; ++k) acc += xr[k] * Wq[(size_t)k * DQ + c];
  qv[b * DQ + c] = (acc * inv + bq[c]) * 0.125f;
}

// K_q3: qk[b,h,D] = Wk[D, h-slice] @ q_h;  cQ[b,h] = q_h . bk_h
__global__ void k_q3(const float* __restrict__ Wk, const float* __restrict__ bk,
                     const float* __restrict__ qv, float* __restrict__ qk,
                     float* __restrict__ cQ) {
  const int bh = blockIdx.x;
  const int b = bh / HQ, h = bh - b * HQ;
  const int tid = threadIdx.x;
  const float* q = qv + b * DQ + h * 64;
#pragma unroll
  for (int j = 0; j < 3; ++j) {
    int dd = tid + j * 256;
    float acc = 0.f;
    for (int j2 = 0; j2 < 64; ++j2) acc += Wk[(size_t)dd * DQ + h * 64 + j2] * q[j2];
    qk[(size_t)bh * DQ + dd] = acc;
  }
  if (tid == 0) {
    float acc = 0.f;
    for (int j2 = 0; j2 < 64; ++j2) acc += q[j2] * bk[h * 64 + j2];
    cQ[bh] = acc;
  }
}

// ---------------- K1: z = ybf @ WyT^T + by (bf16), rowsq += ssq ---------
// m97-clone: 128x128 tile, BK=32, 4 waves (2Mx2N), dbuf 2x16KB.
// Both operands gload_lds width-16, linear 64B rows, 2-bit XOR chunk
// swizzle applied on the global source (read back with chunk q^(r&3)).
#define YB 16384
__global__ __launch_bounds__(256, 4) void k_gemm_yp(const ushort_t* __restrict__ ybf,
                                                    const ushort_t* __restrict__ WyT,
                                                    const float* __restrict__ by,
                                                    ushort_t* __restrict__ z,
                                                    float* __restrict__ rowsqg) {
  __shared__ __align__(16) char smem[2 * YB + 512];
  float* rowsq_l = (float*)(smem + 2 * YB);
  const int tid = threadIdx.x, lane = tid & 63, wv = tid >> 6;
  const int wvM = wv >> 1, wvN = wv & 1;
  // panel-major decode, 8-panel groups share g mod 8 (XCD L2 locality)
  const int g = blockIdx.x;
  const int m = (g / 48) * 8 + (g & 7);
  const int n = (g >> 3) % 6;
  const int mBase = m * 128, nBase = n * 128;

  // staging: 8 A gloads + 8 B gloads per step; this wave does j=2wv,2wv+1
  const int jA0 = wv * 2;
  const ushort_t* aG[2];
  const ushort_t* bG[2];
  int aD[2], bD[2];
#pragma unroll
  for (int j = 0; j < 2; ++j) {
    int r = (jA0 + j) * 16 + (lane >> 2);
    int cs = ((lane & 3) ^ ((lane >> 2) & 3)) * 8;   // pre-swizzled source chunk
    aG[j] = ybf + (size_t)(mBase + r) * DYQ + cs;
    bG[j] = WyT + (size_t)(nBase + r) * DYQ + cs;
    aD[j] = (jA0 + j) * 1024;
    bD[j] = 8192 + (jA0 + j) * 1024;
  }
  // fragment reads: row base + swizzled chunk (q ^ (row&3)); row&3 == lane&3
  const int slotOff = (((lane >> 4) ^ (lane & 3)) * 16);
  int aFr[4], bFr[4];
#pragma unroll
  for (int f = 0; f < 4; ++f) {
    aFr[f] = (wvM * 64 + f * 16 + (lane & 15)) * 64 + slotOff;
    bFr[f] = 8192 + (wvN * 64 + f * 16 + (lane & 15)) * 64 + slotOff;
  }

  f32x4 acc[4][4] = {};
  // prologue: stage t=0 into buf0
#pragma unroll
  for (int j = 0; j < 2; ++j) {
    gload_lds16(aG[j], smem + aD[j]);
    gload_lds16(bG[j], smem + bD[j]);
  }
  __syncthreads();

  for (int t = 0; t < 32; ++t) {
    char* cur = smem + (t & 1) * YB;
    char* nxt = smem + ((t + 1) & 1) * YB;
    if (t < 31) {
#pragma unroll
      for (int j = 0; j < 2; ++j) {
        gload_lds16(aG[j] + (t + 1) * 32, nxt + aD[j]);
        gload_lds16(bG[j] + (t + 1) * 32, nxt + bD[j]);
      }
    }
    short8 af[4], bf[4];
#pragma unroll
    for (int f = 0; f < 4; ++f) af[f] = *(const short8*)(cur + aFr[f]);
#pragma unroll
    for (int f = 0; f < 4; ++f) bf[f] = *(const short8*)(cur + bFr[f]);
#pragma unroll
    for (int nf = 0; nf < 4; ++nf)
#pragma unroll
      for (int mf = 0; mf < 4; ++mf)
        acc[mf][nf] =
            __builtin_amdgcn_mfma_f32_16x16x32_bf16(af[mf], bf[nf], acc[mf][nf], 0, 0, 0);
    __syncthreads();
  }

  // ---- epilogue: +bias, z tile -> LDS (reuse), row ssq partials ----
  if (tid < 128) rowsq_l[tid] = 0.f;
  __syncthreads();
  float byv[4];
#pragma unroll
  for (int nf = 0; nf < 4; ++nf) byv[nf] = by[nBase + wvN * 64 + nf * 16 + (lane & 15)];
#pragma unroll
  for (int mf = 0; mf < 4; ++mf) {
#pragma unroll
    for (int rr = 0; rr < 4; ++rr) {
      int row_l = wvM * 64 + mf * 16 + (lane >> 4) * 4 + rr;
      float ss = 0.f;
#pragma unroll
      for (int nf = 0; nf < 4; ++nf) {
        float zv = acc[mf][nf][rr] + byv[nf];
        ss += zv * zv;
        int col_l = wvN * 64 + nf * 16 + (lane & 15);
        *(ushort_t*)(smem + row_l * 256 + col_l * 2) = f2bf(zv);
      }
#pragma unroll
      for (int o = 1; o < 16; o <<= 1) ss += __shfl_xor(ss, o, 64);
      if ((lane & 15) == 0) atomicAdd(&rowsq_l[row_l], ss);
    }
  }
  __syncthreads();
  if (tid < 128) atomicAdd(&rowsqg[mBase + tid], rowsq_l[tid]);
#pragma unroll
  for (int it = 0; it < 8; ++it) {
    int row = it * 16 + (tid >> 4);
    int ch = tid & 15;
    uint4 v = *(const uint4*)(smem + row * 256 + ch * 16);
    *(uint4*)(z + (size_t)(mBase + row) * DQ + nBase + ch * 8) = v;
  }
}

// ---------------- K2: windowed attention -> p[b,n,h,:] ------------------
__global__ __launch_bounds__(256) void k_attn(const ushort_t* __restrict__ z,
                                              const float* __restrict__ rowsqg,
                                              const float* __restrict__ qk,
                                              const float* __restrict__ cQ,
                                              ushort_t* __restrict__ p) {
  __shared__ __align__(16) char smem[16 * 1552 + 192 * 4 * 2 + 64];
  float* s_l = (float*)(smem + 16 * 1552);
  float* a_l = s_l + 192;
  float* inv_l = a_l + 192;
  const int bn = blockIdx.x, b = bn >> 9;
  const int tid = threadIdx.x;
  if (tid < 16) inv_l[tid] = 1.0f / (sqrtf(rowsqg[bn * 16 + tid]) + 1e-6f);
  for (int j = tid; j < 16 * 96; j += 256) {
    int w = j / 96, ch = j - w * 96;
    *(short8*)(smem + w * 1552 + ch * 16) =
        *(const short8*)(z + ((size_t)bn * 16 + w) * DQ + ch * 8);
  }
  __syncthreads();
  if (tid < 192) {  // (h,w): s = (z_w . qk~) * inv_w + cQ
    int h = tid >> 4, w = tid & 15;
    const float4* qkp = (const float4*)(qk + (size_t)(b * HQ + h) * DQ);
    float acc = 0.f;
    const char* yrow = smem + w * 1552;
    for (int dc = 0; dc < 192; ++dc) {
      float4 q4 = qkp[dc];
      uint2 hh = *(const uint2*)(yrow + dc * 8);
      acc += q4.x * bf2f((ushort_t)(hh.x & 0xffff));
      acc += q4.y * bf2f((ushort_t)(hh.x >> 16));
      acc += q4.z * bf2f((ushort_t)(hh.y & 0xffff));
      acc += q4.w * bf2f((ushort_t)(hh.y >> 16));
    }
    s_l[tid] = acc * inv_l[w] + cQ[b * HQ + h];
  }
  __syncthreads();
  if (tid < 12) {  // softmax over w; fold inv_w into weights
    float mx = -1e30f;
#pragma unroll
    for (int w = 0; w < 16; ++w) mx = fmaxf(mx, s_l[tid * 16 + w]);
    float sm = 0.f, ev[16];
#pragma unroll
    for (int w = 0; w < 16; ++w) {
      ev[w] = __expf(s_l[tid * 16 + w] - mx);
      sm += ev[w];
    }
    float rden = 1.0f / sm;
#pragma unroll
    for (int w = 0; w < 16; ++w) a_l[tid * 16 + w] = ev[w] * rden * inv_l[w];
  }
  __syncthreads();
  // PV with register-cached z columns (3 cols/thread)
  float zr[16][3];
#pragma unroll
  for (int w = 0; w < 16; ++w)
#pragma unroll
    for (int i = 0; i < 3; ++i)
      zr[w][i] = bf2f(*(const ushort_t*)(smem + w * 1552 + (tid + i * 256) * 2));
  for (int h = 0; h < HQ; ++h) {
    float acc0 = 0.f, acc1 = 0.f, acc2 = 0.f;
#pragma unroll
    for (int w = 0; w < 16; ++w) {
      float aw = a_l[h * 16 + w];
      acc0 += aw * zr[w][0];
      acc1 += aw * zr[w][1];
      acc2 += aw * zr[w][2];
    }
    size_t base = ((size_t)bn * HQ + h) * DQ + tid;
    p[base] = f2bf(acc0);
    p[base + 256] = f2bf(acc1);
    p[base + 512] = f2bf(acc2);
  }
}

// ---------------- K3: ctx[:, h*64:(h+1)*64] = p_h @ Wv_h + bv -----------
__global__ __launch_bounds__(256) void k_gemm_pv(const ushort_t* __restrict__ p,
                                                 const ushort_t* __restrict__ WvT,
                                                 const float* __restrict__ bv,
                                                 ushort_t* __restrict__ ctx) {
  __shared__ __align__(16) char smem[2 * 16384];
  const int tid = threadIdx.x, lane = tid & 63, wv = tid >> 6;
  const int wvM = wv >> 1, wvN = wv & 1;
  const int mBase = blockIdx.x * 64, h = blockIdx.y;
  const int ii0 = wv * 2;
  const ushort_t* aG[2];
  const ushort_t* bG[2];
#pragma unroll
  for (int j = 0; j < 2; ++j) {
    int r = (ii0 + j) * 8 + (lane >> 3);
    int sc = ((lane & 7) ^ (lane >> 3)) * 8;
    aG[j] = p + ((size_t)(mBase + r) * HQ + h) * DQ + sc;
    bG[j] = WvT + (size_t)(h * 64 + r) * DQ + sc;
  }
  const int q = lane >> 4;
  int aFr[2], bFr[2];
#pragma unroll
  for (int f = 0; f < 2; ++f) {
    aFr[f] = (wvM * 32 + f * 16 + (lane & 15)) * 128;
    bFr[f] = 8192 + (wvN * 32 + f * 16 + (lane & 15)) * 128;
  }
  const int r7 = lane & 7;
  f32x4 acc[2][2] = {};
#pragma unroll
  for (int j = 0; j < 2; ++j) {
    gload_lds16(aG[j], smem + (ii0 + j) * 1024);
    gload_lds16(bG[j], smem + 8192 + (ii0 + j) * 1024);
  }
  __syncthreads();
  for (int t = 0; t < 12; ++t) {
    char* cur = smem + (t & 1) * 16384;
    char* nxt = smem + ((t + 1) & 1) * 16384;
    if (t < 11) {
#pragma unroll
      for (int j = 0; j < 2; ++j) {
        gload_lds16(aG[j] + (t + 1) * 64, nxt + (ii0 + j) * 1024);
        gload_lds16(bG[j] + (t + 1) * 64, nxt + 8192 + (ii0 + j) * 1024);
      }
    }
#pragma unroll
    for (int ks = 0; ks < 2; ++ks) {
      short8 af[2], bf[2];
#pragma unroll
      for (int f = 0; f < 2; ++f) {
        af[f] = *(const short8*)(cur + aFr[f] + (((ks * 4 + q) ^ r7) * 16));
        bf[f] = *(const short8*)(cur + bFr[f] + (((ks * 4 + q) ^ r7) * 16));
      }
#pragma unroll
      for (int nf = 0; nf < 2; ++nf)
#pragma unroll
        for (int mf = 0; mf < 2; ++mf)
          acc[mf][nf] =
              __builtin_amdgcn_mfma_f32_16x16x32_bf16(af[mf], bf[nf], acc[mf][nf], 0, 0, 0);
    }
    __syncthreads();
  }
#pragma unroll
  for (int nf = 0; nf < 2; ++nf) {
    int col = h * 64 + wvN * 32 + nf * 16 + (lane & 15);
    float bvv = bv[col];
#pragma unroll
    for (int mf = 0; mf < 2; ++mf)
#pragma unroll
      for (int rr = 0; rr < 4; ++rr) {
        int row = mBase + wvM * 32 + mf * 16 + (lane >> 4) * 4 + rr;
        ctx[(size_t)row * DQ + col] = f2bf(acc[mf][nf][rr] + bvv);
      }
  }
}

// ---------------- K4: o = ctx @ Wo + bo (fp32) + row s1/s2 atomics ------
__global__ __launch_bounds__(256) void k_gemm_o(const ushort_t* __restrict__ ctx,
                                                const ushort_t* __restrict__ WoT,
                                                const float* __restrict__ bo,
                                                float* __restrict__ o,
                                                float* __restrict__ oS12) {
  __shared__ __align__(16) char smem[2 * 16384];
  const int tid = threadIdx.x, lane = tid & 63, wv = tid >> 6;
  const int wvM = wv >> 1, wvN = wv & 1;
  const int mBase = blockIdx.x * 64, nBase = blockIdx.y * 64;
  const int ii0 = wv * 2;
  const ushort_t* aG[2];
  const ushort_t* bG[2];
#pragma unroll
  for (int j = 0; j < 2; ++j) {
    int r = (ii0 + j) * 8 + (lane >> 3);
    int sc = ((lane & 7) ^ (lane >> 3)) * 8;
    aG[j] = ctx + (size_t)(mBase + r) * DQ + sc;
    bG[j] = WoT + (size_t)(nBase + r) * DQ + sc;
  }
  const int q = lane >> 4;
  int aFr[2], bFr[2];
#pragma unroll
  for (int f = 0; f < 2; ++f) {
    aFr[f] = (wvM * 32 + f * 16 + (lane & 15)) * 128;
    bFr[f] = 8192 + (wvN * 32 + f * 16 + (lane & 15)) * 128;
  }
  const int r7 = lane & 7;
  f32x4 acc[2][2] = {};
#pragma unroll
  for (int j = 0; j < 2; ++j) {
    gload_lds16(aG[j], smem + (ii0 + j) * 1024);
    gload_lds16(bG[j], smem + 8192 + (ii0 + j) * 1024);
  }
  __syncthreads();
  for (int t = 0; t < 12; ++t) {
    char* cur = smem + (t & 1) * 16384;
    char* nxt = smem + ((t + 1) & 1) * 16384;
    if (t < 11) {
#pragma unroll
      for (int j = 0; j < 2; ++j) {
        gload_lds16(aG[j] + (t + 1) * 64, nxt + (ii0 + j) * 1024);
        gload_lds16(bG[j] + (t + 1) * 64, nxt + 8192 + (ii0 + j) * 1024);
      }
    }
#pragma unroll
    for (int ks = 0; ks < 2; ++ks) {
      short8 af[2], bf[2];
#pragma unroll
      for (int f = 0; f < 2; ++f) {
        af[f] = *(const short8*)(cur + aFr[f] + (((ks * 4 + q) ^ r7) * 16));
        bf[f] = *(const short8*)(cur + bFr[f] + (((ks * 4 + q) ^ r7) * 16));
      }
#pragma unroll
      for (int nf = 0; nf < 2; ++nf)
#pragma unroll
        for (int mf = 0; mf < 2; ++mf)
          acc[mf][nf] =
              __builtin_amdgcn_mfma_f32_16x16x32_bf16(af[mf], bf[nf], acc[mf][nf], 0, 0, 0);
    }
    __syncthreads();
  }
  float bo0 = bo[nBase + wvN * 32 + (lane & 15)];
  float bo1 = bo[nBase + wvN * 32 + 16 + (lane & 15)];
#pragma unroll
  for (int mf = 0; mf < 2; ++mf)
#pragma unroll
    for (int rr = 0; rr < 4; ++rr) {
      int row = mBase + wvM * 32 + mf * 16 + (lane >> 4) * 4 + rr;
      float z0 = acc[mf][0][rr] + bo0;
      float z1 = acc[mf][1][rr] + bo1;
      o[(size_t)row * DQ + nBase + wvN * 32 + (lane & 15)] = z0;
      o[(size_t)row * DQ + nBase + wvN * 32 + 16 + (lane & 15)] = z1;
      float s1 = z0 + z1, s2 = z0 * z0 + z1 * z1;
#pragma unroll
      for (int ofs = 1; ofs < 16; ofs <<= 1) {
        s1 += __shfl_xor(s1, ofs, 64);
        s2 += __shfl_xor(s2, ofs, 64);
      }
      if ((lane & 15) == 0) {
        atomicAdd(&oS12[row], s1);
        atomicAdd(&oS12[BN_ROWS + row], s2);
      }
    }
}

// K5: LayerNorm finalize -> out row positions
__global__ __launch_bounds__(256) void k_final(const float* __restrict__ o,
                                               const float* __restrict__ oS12,
                                               const float* __restrict__ ln_g,
                                               const float* __restrict__ ln_b,
                                               float* __restrict__ out) {
  const int tid = threadIdx.x;
  const int row = blockIdx.x * 8 + (tid >> 5);
  const int l32 = tid & 31;
  float mu = oS12[row] * (1.0f / DQ);
  float va = oS12[BN_ROWS + row] * (1.0f / DQ) - mu * mu;
  float rstd = rsqrtf(va + 1e-6f);
  int b = row >> 9, n = row & 511;
  size_t obase = ((size_t)b * (NXQ * (PQ + 1)) + (size_t)n * (PQ + 1)) * DQ;
#pragma unroll
  for (int j = 0; j < 6; ++j) {
    int c4 = l32 + j * 32;
    float4 v = ((const float4*)(o + (size_t)row * DQ))[c4];
    float4 g = ((const float4*)ln_g)[c4];
    float4 bb = ((const float4*)ln_b)[c4];
    float4 r;
    r.x = (v.x - mu) * rstd * g.x + bb.x;
    r.y = (v.y - mu) * rstd * g.y + bb.y;
    r.z = (v.z - mu) * rstd * g.z + bb.z;
    r.w = (v.w - mu) * rstd * g.w + bb.w;
    ((float4*)(out + obase))[c4] = r;
  }
}

// K6: broadcast prompt rows
__global__ void k_prompt(const float* __restrict__ prompt, float* __restrict__ out) {
  const int N4 = BQ * NXQ * PQ * (DQ / 4);
  for (int j = blockIdx.x * blockDim.x + threadIdx.x; j < N4;
       j += gridDim.x * blockDim.x) {
    int d4 = j % (DQ / 4);
    int rest = j / (DQ / 4);
    int pi = rest % PQ;
    int rest2 = rest / PQ;
    int n = rest2 % NXQ;
    int b = rest2 / NXQ;
    float4 v = ((const float4*)prompt)[pi * (DQ / 4) + d4];
    ((float4*)out)[((size_t)b * (NXQ * 9) + (size_t)n * 9 + 1 + pi) * (DQ / 4) + d4] = v;
  }
}

extern "C" void kernel_launch(void* const* d_in, const int* in_sizes, int n_in,
                              void* d_out, int out_size, void* d_ws, size_t ws_size,
                              hipStream_t stream) {
  (void)in_sizes; (void)n_in; (void)out_size; (void)ws_size;
  const float* x    = (const float*)d_in[0];
  const float* y    = (const float*)d_in[1];
  const float* Wx   = (const float*)d_in[2];
  const float* bx   = (const float*)d_in[3];
  const float* Wy   = (const float*)d_in[4];
  const float* by   = (const float*)d_in[5];
  const float* prom = (const float*)d_in[6];
  const float* Wq   = (const float*)d_in[7];
  const float* bq   = (const float*)d_in[8];
  const float* Wk   = (const float*)d_in[9];
  const float* bk   = (const float*)d_in[10];
  const float* Wv   = (const float*)d_in[11];
  const float* bv   = (const float*)d_in[12];
  const float* Wo   = (const float*)d_in[13];
  const float* bo   = (const float*)d_in[14];
  const float* lng  = (const float*)d_in[15];
  const float* lnb  = (const float*)d_in[16];
  float* out = (float*)d_out;
  char* ws = (char*)d_ws;

  // ---- workspace layout (aliased; ~240 MB total) ----
  size_t oWyT = 0;                                    // 1.57 MB
  size_t oWvT = oWyT + (size_t)DQ * DYQ * 2;          // 1.18 MB
  size_t oWoT = oWvT + (size_t)DQ * DQ * 2;           // 1.18 MB
  size_t oXw  = oWoT + (size_t)DQ * DQ * 2;           // 24 KB
  size_t oXss = oXw + (size_t)BQ * DQ * 4;            // 32 B -> pad
  size_t oQ   = oXss + 256;                           // 24 KB
  size_t oQK  = oQ + (size_t)BQ * DQ * 4;             // 294 KB
  size_t oC   = oQK + (size_t)BQ * HQ * DQ * 4;       // 1 KB
  size_t oRq  = oC + 1024;                            // 256 KB
  size_t oS   = oRq + (size_t)MY * 4;                 // 32 KB
  size_t oYbf = oS + (size_t)2 * BN_ROWS * 4;         // 134.2 MB
  size_t oZ   = oYbf + (size_t)MY * DYQ * 2;          // 100.7 MB
  // aliases: p, ctx inside ybf (dead after gemm); o inside z (dead after attn)
  size_t oP   = oYbf;                                 // 75.5 MB
  size_t oCtx = oYbf + (size_t)BN_ROWS * HQ * DQ * 2; // 6.3 MB
  size_t oO   = oZ;                                   // 12.6 MB

  ushort_t* WyT = (ushort_t*)(ws + oWyT);
  ushort_t* WvT = (ushort_t*)(ws + oWvT);
  ushort_t* WoT = (ushort_t*)(ws + oWoT);
  float* xw  = (float*)(ws + oXw);
  float* xss = (float*)(ws + oXss);
  float* qv  = (float*)(ws + oQ);
  float* qk  = (float*)(ws + oQK);
  float* cQ  = (float*)(ws + oC);
  float* rowsq = (float*)(ws + oRq);
  float* oS12  = (float*)(ws + oS);
  ushort_t* ybf  = (ushort_t*)(ws + oYbf);
  ushort_t* zbuf = (ushort_t*)(ws + oZ);
  ushort_t* p    = (ushort_t*)(ws + oP);
  ushort_t* ctx  = (ushort_t*)(ws + oCtx);
  float* obuf    = (float*)(ws + oO);

  k_conv<<<dim3(4096), dim3(256), 0, stream>>>(y, Wy, Wv, Wo, ybf, WyT, WvT, WoT,
                                               rowsq, oS12, xss);
  k_q1<<<dim3(BQ, 6), dim3(128), 0, stream>>>(x, Wx, bx, xw, xss);
  k_q2<<<dim3(BQ, 6), dim3(128), 0, stream>>>(xw, xss, Wq, bq, qv);
  k_q3<<<dim3(BQ * HQ), dim3(256), 0, stream>>>(Wk, bk, qv, qk, cQ);
  k_gemm_yp<<<dim3(3072), dim3(256), 0, stream>>>(ybf, WyT, by, zbuf, rowsq);
  k_attn<<<dim3(BN_ROWS), dim3(256), 0, stream>>>(zbuf, rowsq, qk, cQ, p);
  k_gemm_pv<<<dim3(BN_ROWS / 64, HQ), dim3(256), 0, stream>>>(p, WvT, bv, ctx);
  k_gemm_o<<<dim3(BN_ROWS / 64, DQ / 64), dim3(256), 0, stream>>>(ctx, WoT, bo, obuf, oS12);
  k_final<<<dim3(BN_ROWS / 8), dim3(256), 0, stream>>>(obuf, oS12, lng, lnb, out);
  k_prompt<<<dim3(2048), dim3(256), 0, stream>>>(prom, out);
}

// Round 5
// 471.380 us; speedup vs baseline: 1.4058x; 1.1772x over previous
//
#include <hip/hip_runtime.h>
#include <stdint.h>

// Problem constants
#define BQ 8
#define NXQ 512
#define WQ 16
#define DXQ 1536
#define DYQ 1024
#define DQ 768
#define HQ 12
#define PQ 8
// derived
#define MY 65536            // B*NX*W rows of y
#define BN_ROWS 4096        // B*NX

typedef __attribute__((ext_vector_type(8))) short short8;
typedef __attribute__((ext_vector_type(4))) float f32x4;
typedef unsigned short ushort_t;
typedef unsigned int uint_t;

__device__ __forceinline__ ushort_t f2bf(float f) {
  uint_t u = __float_as_uint(f);
  u += 0x7FFFu + ((u >> 16) & 1u);   // RNE
  return (ushort_t)(u >> 16);
}
__device__ __forceinline__ float bf2f(ushort_t h) {
  return __uint_as_float(((uint_t)h) << 16);
}
__device__ __forceinline__ void gload_lds16(const void* g, void* l) {
  __builtin_amdgcn_global_load_lds(
      (__attribute__((address_space(1))) unsigned int*)(g),
      (__attribute__((address_space(3))) unsigned int*)(l), 16, 0, 0);
}

// ---------------- K0: y->bf16, weight transposes, zero accumulators -----
__global__ void k_conv(const float* __restrict__ y, const float* __restrict__ Wy,
                       const float* __restrict__ Wv, const float* __restrict__ Wo,
                       ushort_t* __restrict__ ybf, ushort_t* __restrict__ WyT,
                       ushort_t* __restrict__ WvT, ushort_t* __restrict__ WoT,
                       float* __restrict__ rowsq, float* __restrict__ oS12,
                       float* __restrict__ xw) {
  const int gstride = gridDim.x * blockDim.x;
  const int g0 = blockIdx.x * blockDim.x + threadIdx.x;
  // y fp32 -> bf16
  const int NY8 = MY * DYQ / 8;
  for (int i = g0; i < NY8; i += gstride) {
    const float4* s = (const float4*)(y + (size_t)i * 8);
    float4 f0 = s[0], f1 = s[1];
    short8 hv;
    hv[0] = (short)f2bf(f0.x); hv[1] = (short)f2bf(f0.y);
    hv[2] = (short)f2bf(f0.z); hv[3] = (short)f2bf(f0.w);
    hv[4] = (short)f2bf(f1.x); hv[5] = (short)f2bf(f1.y);
    hv[6] = (short)f2bf(f1.z); hv[7] = (short)f2bf(f1.w);
    *(short8*)(ybf + (size_t)i * 8) = hv;
  }
  // zeros
  for (int i = g0; i < MY; i += gstride) rowsq[i] = 0.f;
  for (int i = g0; i < 2 * BN_ROWS; i += gstride) oS12[i] = 0.f;
  for (int i = g0; i < BQ * DQ; i += gstride) xw[i] = 0.f;
  // weight transposes (bf16)
  const int N1 = DQ * DYQ;
  const int N2 = DQ * DQ;
  const int total = N1 + 2 * N2;
  for (int i = g0; i < total; i += gstride) {
    if (i < N1) {
      int n = i / DYQ, k = i - n * DYQ;
      WyT[i] = f2bf(Wy[k * DQ + n]);
    } else if (i < N1 + N2) {
      int j = i - N1;
      int n = j / DQ, k = j - n * DQ;
      WvT[j] = f2bf(Wv[k * DQ + n]);
    } else {
      int j = i - N1 - N2;
      int n = j / DQ, k = j - n * DQ;
      WoT[j] = f2bf(Wo[k * DQ + n]);
    }
  }
}

// ---------------- q-chain ------------------------------------------------
// K_q1 (split-k): xw[b,c] += x[b,0,kc-slice] @ Wx[kc-slice,c] (+bx once)
__global__ __launch_bounds__(128) void k_q1(const float* __restrict__ x,
                                            const float* __restrict__ Wx,
                                            const float* __restrict__ bx,
                                            float* __restrict__ xw) {
  const int b = blockIdx.x, c = blockIdx.y * 128 + threadIdx.x;
  const int kc = blockIdx.z;
  const float* xr = x + (size_t)b * NXQ * DXQ + kc * 192;
  const float* wp = Wx + (size_t)kc * 192 * DQ + c;
  float acc = (kc == 0) ? bx[c] : 0.f;
  for (int k = 0; k < 192; ++k) acc += xr[k] * wp[(size_t)k * DQ];
  atomicAdd(&xw[b * DQ + c], acc);
}

// K_q2: q[b,c] = ((xw[b,:]*inv_b) @ Wq[:,c] + bq[c]) * 0.125 ; inv from xw
__global__ __launch_bounds__(128) void k_q2(const float* __restrict__ xw,
                                            const float* __restrict__ Wq,
                                            const float* __restrict__ bq,
                                            float* __restrict__ qv) {
  const int b = blockIdx.x, c = blockIdx.y * 128 + threadIdx.x;
  const float* xr = xw + b * DQ;
  float acc = 0.f, ss = 0.f;
  for (int k = 0; k < DQ; ++k) {
    float v = xr[k];
    acc += v * Wq[(size_t)k * DQ + c];
    ss += v * v;
  }
  const float inv = 1.0f / (sqrtf(ss) + 1e-6f);
  qv[b * DQ + c] = (acc * inv + bq[c]) * 0.125f;
}

// K_q3: qk[b,h,D] = Wk[D, h-slice] @ q_h;  cQ[b,h] = q_h . bk_h
__global__ void k_q3(const float* __restrict__ Wk, const float* __restrict__ bk,
                     const float* __restrict__ qv, float* __restrict__ qk,
                     float* __restrict__ cQ) {
  const int bh = blockIdx.x;
  const int b = bh / HQ, h = bh - b * HQ;
  const int tid = threadIdx.x;
  const float* q = qv + b * DQ + h * 64;
#pragma unroll
  for (int j = 0; j < 3; ++j) {
    int dd = tid + j * 256;
    float acc = 0.f;
    for (int j2 = 0; j2 < 64; ++j2) acc += Wk[(size_t)dd * DQ + h * 64 + j2] * q[j2];
    qk[(size_t)bh * DQ + dd] = acc;
  }
  if (tid == 0) {
    float acc = 0.f;
    for (int j2 = 0; j2 < 64; ++j2) acc += q[j2] * bk[h * 64 + j2];
    cQ[bh] = acc;
  }
}

// ---------------- K1: z = ybf @ WyT^T + by (bf16), rowsq += ssq ---------
// BM=256, BN=128, BK=64, 8 waves (2M x 4N), 3-deep LDS rotation with
// counted vmcnt(6) (T4), raw s_barrier, T2 3-bit XOR chunk swizzle
// (pre-applied on global source; inverse on fragment read), T5 setprio.
#define YP_TSZ 49152         // A 32KB + B 16KB per K-tile
#define YP_NT 16
__global__ __launch_bounds__(512) void k_gemm_yp(const ushort_t* __restrict__ ybf,
                                                 const ushort_t* __restrict__ WyT,
                                                 const float* __restrict__ by,
                                                 ushort_t* __restrict__ z,
                                                 float* __restrict__ rowsqg) {
  __shared__ __align__(16) char smem[3 * YP_TSZ + 1024];
  float* rowsq_l = (float*)(smem + 3 * YP_TSZ);
  const int tid = threadIdx.x, lane = tid & 63, wv = tid >> 6;
  const int wvM = wv >> 2, wvN = wv & 3;
  // panel-major decode: 6 consecutive-N blocks share g mod 8 (XCD L2)
  const int g = blockIdx.x;
  const int m = (g / 48) * 8 + (g & 7);
  const int n = (g >> 3) % 6;
  const int mBase = m * 256, nBase = n * 128;
  if (tid < 256) rowsq_l[tid] = 0.f;

  // staging addresses: each gload covers 8 rows x 128B; chunk pre-swizzled
  const int l8 = lane >> 3;
  const int c8 = (lane & 7) ^ (l8 & 7);
  const ushort_t* aSrc[4]; const ushort_t* bSrc[2];
  int aDst[4], bDst[2];
#pragma unroll
  for (int j = 0; j < 4; ++j) {
    int r = wv * 32 + j * 8 + l8;
    aSrc[j] = ybf + (size_t)(mBase + r) * DYQ + c8 * 8;
    aDst[j] = (wv * 32 + j * 8) * 128;
  }
#pragma unroll
  for (int j = 0; j < 2; ++j) {
    int r = wv * 16 + j * 8 + l8;
    bSrc[j] = WyT + (size_t)(nBase + r) * DYQ + c8 * 8;
    bDst[j] = 32768 + (wv * 16 + j * 8) * 128;
  }
  // fragment read bases; phys chunk = (ks*4 + q) ^ (row & 7)
  const int q = lane >> 4;
  int aRowB[8], aSw[8], bRowB[2], bSw[2];
#pragma unroll
  for (int mf = 0; mf < 8; ++mf) {
    int r = wvM * 128 + mf * 16 + (lane & 15);
    aRowB[mf] = r * 128; aSw[mf] = r & 7;
  }
#pragma unroll
  for (int nf = 0; nf < 2; ++nf) {
    int r = wvN * 32 + nf * 16 + (lane & 15);
    bRowB[nf] = 32768 + r * 128; bSw[nf] = r & 7;
  }

#define YP_STAGE(dbuf, t)                                                      \
  {                                                                            \
    char* db = smem + (dbuf) * YP_TSZ;                                         \
    _Pragma("unroll") for (int j = 0; j < 4; ++j)                              \
        gload_lds16(aSrc[j] + (t) * 64, db + aDst[j]);                         \
    _Pragma("unroll") for (int j = 0; j < 2; ++j)                              \
        gload_lds16(bSrc[j] + (t) * 64, db + bDst[j]);                         \
  }

  f32x4 acc[8][2] = {};
  YP_STAGE(0, 0);
  YP_STAGE(1, 1);
  int bR = 0, bS = 2;
  for (int t = 0; t < YP_NT; ++t) {
    if (t < YP_NT - 1) {
      asm volatile("s_waitcnt vmcnt(6)" ::: "memory");   // own tile-t loads landed
    } else {
      asm volatile("s_waitcnt vmcnt(0)" ::: "memory");
    }
    __builtin_amdgcn_s_barrier();                        // all waves' loads landed
    __builtin_amdgcn_sched_barrier(0);
    if (t + 2 < YP_NT) YP_STAGE(bS, t + 2);              // buffer last read at t-1
    const char* cur = smem + bR * YP_TSZ;
#pragma unroll
    for (int ks = 0; ks < 2; ++ks) {
      short8 af[8], bf[2];
#pragma unroll
      for (int mf = 0; mf < 8; ++mf)
        af[mf] = *(const short8*)(cur + aRowB[mf] + (((ks * 4 + q) ^ aSw[mf]) << 4));
#pragma unroll
      for (int nf = 0; nf < 2; ++nf)
        bf[nf] = *(const short8*)(cur + bRowB[nf] + (((ks * 4 + q) ^ bSw[nf]) << 4));
      __builtin_amdgcn_s_setprio(1);
#pragma unroll
      for (int nf = 0; nf < 2; ++nf)
#pragma unroll
        for (int mf = 0; mf < 8; ++mf)
          acc[mf][nf] = __builtin_amdgcn_mfma_f32_16x16x32_bf16(af[mf], bf[nf],
                                                                acc[mf][nf], 0, 0, 0);
      __builtin_amdgcn_s_setprio(0);
    }
    __builtin_amdgcn_sched_barrier(0);
    bR = (bR == 2) ? 0 : bR + 1;
    bS = (bS == 2) ? 0 : bS + 1;
  }
  __syncthreads();

  // ---- epilogue: +bias, z tile (256x128) -> LDS, row ssq partials ----
  float byv[2];
#pragma unroll
  for (int nf = 0; nf < 2; ++nf) byv[nf] = by[nBase + wvN * 32 + nf * 16 + (lane & 15)];
#pragma unroll
  for (int mf = 0; mf < 8; ++mf) {
#pragma unroll
    for (int rr = 0; rr < 4; ++rr) {
      int row_l = wvM * 128 + mf * 16 + (lane >> 4) * 4 + rr;
      float ss = 0.f;
#pragma unroll
      for (int nf = 0; nf < 2; ++nf) {
        float zv = acc[mf][nf][rr] + byv[nf];
        ss += zv * zv;
        int col_l = wvN * 32 + nf * 16 + (lane & 15);
        *(ushort_t*)(smem + row_l * 256 + col_l * 2) = f2bf(zv);
      }
#pragma unroll
      for (int o = 1; o < 16; o <<= 1) ss += __shfl_xor(ss, o, 64);
      if ((lane & 15) == 0) atomicAdd(&rowsq_l[row_l], ss);
    }
  }
  __syncthreads();
  if (tid < 256) atomicAdd(&rowsqg[mBase + tid], rowsq_l[tid]);
#pragma unroll
  for (int it = 0; it < 8; ++it) {
    int row = it * 32 + (tid >> 4);
    int ch = tid & 15;
    uint4 v = *(const uint4*)(smem + row * 256 + ch * 16);
    *(uint4*)(z + (size_t)(mBase + row) * DQ + nBase + ch * 8) = v;
  }
}

// ---------------- K2: windowed attention -> p[b,n,h,:] ------------------
__global__ __launch_bounds__(256) void k_attn(const ushort_t* __restrict__ z,
                                              const float* __restrict__ rowsqg,
                                              const float* __restrict__ qk,
                                              const float* __restrict__ cQ,
                                              ushort_t* __restrict__ p) {
  __shared__ __align__(16) char smem[16 * 1552 + 192 * 4 * 2 + 64];
  float* s_l = (float*)(smem + 16 * 1552);
  float* a_l = s_l + 192;
  float* inv_l = a_l + 192;
  const int bn = blockIdx.x, b = bn >> 9;
  const int tid = threadIdx.x;
  if (tid < 16) inv_l[tid] = 1.0f / (sqrtf(rowsqg[bn * 16 + tid]) + 1e-6f);
  for (int j = tid; j < 16 * 96; j += 256) {
    int w = j / 96, ch = j - w * 96;
    *(short8*)(smem + w * 1552 + ch * 16) =
        *(const short8*)(z + ((size_t)bn * 16 + w) * DQ + ch * 8);
  }
  __syncthreads();
  if (tid < 192) {  // (h,w): s = (z_w . qk~) * inv_w + cQ
    int h = tid >> 4, w = tid & 15;
    const float4* qkp = (const float4*)(qk + (size_t)(b * HQ + h) * DQ);
    float acc = 0.f;
    const char* yrow = smem + w * 1552;
    for (int dc = 0; dc < 192; ++dc) {
      float4 q4 = qkp[dc];
      uint2 hh = *(const uint2*)(yrow + dc * 8);
      acc += q4.x * bf2f((ushort_t)(hh.x & 0xffff));
      acc += q4.y * bf2f((ushort_t)(hh.x >> 16));
      acc += q4.z * bf2f((ushort_t)(hh.y & 0xffff));
      acc += q4.w * bf2f((ushort_t)(hh.y >> 16));
    }
    s_l[tid] = acc * inv_l[w] + cQ[b * HQ + h];
  }
  __syncthreads();
  if (tid < 12) {  // softmax over w; fold inv_w into weights
    float mx = -1e30f;
#pragma unroll
    for (int w = 0; w < 16; ++w) mx = fmaxf(mx, s_l[tid * 16 + w]);
    float sm = 0.f, ev[16];
#pragma unroll
    for (int w = 0; w < 16; ++w) {
      ev[w] = __expf(s_l[tid * 16 + w] - mx);
      sm += ev[w];
    }
    float rden = 1.0f / sm;
#pragma unroll
    for (int w = 0; w < 16; ++w) a_l[tid * 16 + w] = ev[w] * rden * inv_l[w];
  }
  __syncthreads();
  float zr[16][3];
#pragma unroll
  for (int w = 0; w < 16; ++w)
#pragma unroll
    for (int i = 0; i < 3; ++i)
      zr[w][i] = bf2f(*(const ushort_t*)(smem + w * 1552 + (tid + i * 256) * 2));
  for (int h = 0; h < HQ; ++h) {
    float acc0 = 0.f, acc1 = 0.f, acc2 = 0.f;
#pragma unroll
    for (int w = 0; w < 16; ++w) {
      float aw = a_l[h * 16 + w];
      acc0 += aw * zr[w][0];
      acc1 += aw * zr[w][1];
      acc2 += aw * zr[w][2];
    }
    size_t base = ((size_t)bn * HQ + h) * DQ + tid;
    p[base] = f2bf(acc0);
    p[base + 256] = f2bf(acc1);
    p[base + 512] = f2bf(acc2);
  }
}

// ---------------- K3: ctx[:, h*64:(h+1)*64] = p_h @ Wv_h + bv -----------
// 128x64 tile, K=768 (12 BK=64 tiles), 4 waves (2Mx2N), 3-deep counted vmcnt.
#define PV_TSZ 24576         // A 16KB + B 8KB
__global__ __launch_bounds__(256) void k_gemm_pv(const ushort_t* __restrict__ p,
                                                 const ushort_t* __restrict__ WvT,
                                                 const float* __restrict__ bv,
                                                 ushort_t* __restrict__ ctx) {
  __shared__ __align__(16) char smem[3 * PV_TSZ];
  const int tid = threadIdx.x, lane = tid & 63, wv = tid >> 6;
  const int wvM = wv >> 1, wvN = wv & 1;
  const int mBase = blockIdx.x * 128, h = blockIdx.y;
  const int l8 = lane >> 3;
  const int c8 = (lane & 7) ^ (l8 & 7);
  const ushort_t* aSrc[4]; const ushort_t* bSrc[2];
  int aDst[4], bDst[2];
#pragma unroll
  for (int j = 0; j < 4; ++j) {
    int r = wv * 32 + j * 8 + l8;
    aSrc[j] = p + ((size_t)(mBase + r) * HQ + h) * DQ + c8 * 8;
    aDst[j] = (wv * 32 + j * 8) * 128;
  }
#pragma unroll
  for (int j = 0; j < 2; ++j) {
    int r = wv * 16 + j * 8 + l8;
    bSrc[j] = WvT + (size_t)(h * 64 + r) * DQ + c8 * 8;
    bDst[j] = 16384 + (wv * 16 + j * 8) * 128;
  }
  const int q = lane >> 4;
  int aRowB[4], aSw[4], bRowB[2], bSw[2];
#pragma unroll
  for (int mf = 0; mf < 4; ++mf) {
    int r = wvM * 64 + mf * 16 + (lane & 15);
    aRowB[mf] = r * 128; aSw[mf] = r & 7;
  }
#pragma unroll
  for (int nf = 0; nf < 2; ++nf) {
    int r = wvN * 32 + nf * 16 + (lane & 15);
    bRowB[nf] = 16384 + r * 128; bSw[nf] = r & 7;
  }
#define PV_STAGE(dbuf, t)                                                      \
  {                                                                            \
    char* db = smem + (dbuf) * PV_TSZ;                                         \
    _Pragma("unroll") for (int j = 0; j < 4; ++j)                              \
        gload_lds16(aSrc[j] + (t) * 64, db + aDst[j]);                         \
    _Pragma("unroll") for (int j = 0; j < 2; ++j)                              \
        gload_lds16(bSrc[j] + (t) * 64, db + bDst[j]);                         \
  }
  f32x4 acc[4][2] = {};
  PV_STAGE(0, 0);
  PV_STAGE(1, 1);
  int bR = 0, bS = 2;
  for (int t = 0; t < 12; ++t) {
    if (t < 11) {
      asm volatile("s_waitcnt vmcnt(6)" ::: "memory");
    } else {
      asm volatile("s_waitcnt vmcnt(0)" ::: "memory");
    }
    __builtin_amdgcn_s_barrier();
    __builtin_amdgcn_sched_barrier(0);
    if (t + 2 < 12) PV_STAGE(bS, t + 2);
    const char* cur = smem + bR * PV_TSZ;
#pragma unroll
    for (int ks = 0; ks < 2; ++ks) {
      short8 af[4], bf[2];
#pragma unroll
      for (int mf = 0; mf < 4; ++mf)
        af[mf] = *(const short8*)(cur + aRowB[mf] + (((ks * 4 + q) ^ aSw[mf]) << 4));
#pragma unroll
      for (int nf = 0; nf < 2; ++nf)
        bf[nf] = *(const short8*)(cur + bRowB[nf] + (((ks * 4 + q) ^ bSw[nf]) << 4));
      __builtin_amdgcn_s_setprio(1);
#pragma unroll
      for (int nf = 0; nf < 2; ++nf)
#pragma unroll
        for (int mf = 0; mf < 4; ++mf)
          acc[mf][nf] = __builtin_amdgcn_mfma_f32_16x16x32_bf16(af[mf], bf[nf],
                                                                acc[mf][nf], 0, 0, 0);
      __builtin_amdgcn_s_setprio(0);
    }
    __builtin_amdgcn_sched_barrier(0);
    bR = (bR == 2) ? 0 : bR + 1;
    bS = (bS == 2) ? 0 : bS + 1;
  }
#pragma unroll
  for (int nf = 0; nf < 2; ++nf) {
    int col = h * 64 + wvN * 32 + nf * 16 + (lane & 15);
    float bvv = bv[col];
#pragma unroll
    for (int mf = 0; mf < 4; ++mf)
#pragma unroll
      for (int rr = 0; rr < 4; ++rr) {
        int row = mBase + wvM * 64 + mf * 16 + (lane >> 4) * 4 + rr;
        ctx[(size_t)row * DQ + col] = f2bf(acc[mf][nf][rr] + bvv);
      }
  }
}

// ---------------- K4: o = ctx @ Wo + bo (fp32) + row s1/s2 atomics ------
__global__ __launch_bounds__(256) void k_gemm_o(const ushort_t* __restrict__ ctx,
                                                const ushort_t* __restrict__ WoT,
                                                const float* __restrict__ bo,
                                                float* __restrict__ o,
                                                float* __restrict__ oS12) {
  __shared__ __align__(16) char smem[3 * PV_TSZ];
  const int tid = threadIdx.x, lane = tid & 63, wv = tid >> 6;
  const int wvM = wv >> 1, wvN = wv & 1;
  const int mBase = blockIdx.x * 128, nBase = blockIdx.y * 64;
  const int l8 = lane >> 3;
  const int c8 = (lane & 7) ^ (l8 & 7);
  const ushort_t* aSrc[4]; const ushort_t* bSrc[2];
  int aDst[4], bDst[2];
#pragma unroll
  for (int j = 0; j < 4; ++j) {
    int r = wv * 32 + j * 8 + l8;
    aSrc[j] = ctx + (size_t)(mBase + r) * DQ + c8 * 8;
    aDst[j] = (wv * 32 + j * 8) * 128;
  }
#pragma unroll
  for (int j = 0; j < 2; ++j) {
    int r = wv * 16 + j * 8 + l8;
    bSrc[j] = WoT + (size_t)(nBase + r) * DQ + c8 * 8;
    bDst[j] = 16384 + (wv * 16 + j * 8) * 128;
  }
  const int q = lane >> 4;
  int aRowB[4], aSw[4], bRowB[2], bSw[2];
#pragma unroll
  for (int mf = 0; mf < 4; ++mf) {
    int r = wvM * 64 + mf * 16 + (lane & 15);
    aRowB[mf] = r * 128; aSw[mf] = r & 7;
  }
#pragma unroll
  for (int nf = 0; nf < 2; ++nf) {
    int r = wvN * 32 + nf * 16 + (lane & 15);
    bRowB[nf] = 16384 + r * 128; bSw[nf] = r & 7;
  }
  f32x4 acc[4][2] = {};
#define O_STAGE(dbuf, t)                                                       \
  {                                                                            \
    char* db = smem + (dbuf) * PV_TSZ;                                         \
    _Pragma("unroll") for (int j = 0; j < 4; ++j)                              \
        gload_lds16(aSrc[j] + (t) * 64, db + aDst[j]);                         \
    _Pragma("unroll") for (int j = 0; j < 2; ++j)                              \
        gload_lds16(bSrc[j] + (t) * 64, db + bDst[j]);                         \
  }
  O_STAGE(0, 0);
  O_STAGE(1, 1);
  int bR = 0, bS = 2;
  for (int t = 0; t < 12; ++t) {
    if (t < 11) {
      asm volatile("s_waitcnt vmcnt(6)" ::: "memory");
    } else {
      asm volatile("s_waitcnt vmcnt(0)" ::: "memory");
    }
    __builtin_amdgcn_s_barrier();
    __builtin_amdgcn_sched_barrier(0);
    if (t + 2 < 12) O_STAGE(bS, t + 2);
    const char* cur = smem + bR * PV_TSZ;
#pragma unroll
    for (int ks = 0; ks < 2; ++ks) {
      short8 af[4], bf[2];
#pragma unroll
      for (int mf = 0; mf < 4; ++mf)
        af[mf] = *(const short8*)(cur + aRowB[mf] + (((ks * 4 + q) ^ aSw[mf]) << 4));
#pragma unroll
      for (int nf = 0; nf < 2; ++nf)
        bf[nf] = *(const short8*)(cur + bRowB[nf] + (((ks * 4 + q) ^ bSw[nf]) << 4));
      __builtin_amdgcn_s_setprio(1);
#pragma unroll
      for (int nf = 0; nf < 2; ++nf)
#pragma unroll
        for (int mf = 0; mf < 4; ++mf)
          acc[mf][nf] = __builtin_amdgcn_mfma_f32_16x16x32_bf16(af[mf], bf[nf],
                                                                acc[mf][nf], 0, 0, 0);
      __builtin_amdgcn_s_setprio(0);
    }
    __builtin_amdgcn_sched_barrier(0);
    bR = (bR == 2) ? 0 : bR + 1;
    bS = (bS == 2) ? 0 : bS + 1;
  }
  float bo0 = bo[nBase + wvN * 32 + (lane & 15)];
  float bo1 = bo[nBase + wvN * 32 + 16 + (lane & 15)];
#pragma unroll
  for (int mf = 0; mf < 4; ++mf)
#pragma unroll
    for (int rr = 0; rr < 4; ++rr) {
      int row = mBase + wvM * 64 + mf * 16 + (lane >> 4) * 4 + rr;
      float z0 = acc[mf][0][rr] + bo0;
      float z1 = acc[mf][1][rr] + bo1;
      o[(size_t)row * DQ + nBase + wvN * 32 + (lane & 15)] = z0;
      o[(size_t)row * DQ + nBase + wvN * 32 + 16 + (lane & 15)] = z1;
      float s1 = z0 + z1, s2 = z0 * z0 + z1 * z1;
#pragma unroll
      for (int ofs = 1; ofs < 16; ofs <<= 1) {
        s1 += __shfl_xor(s1, ofs, 64);
        s2 += __shfl_xor(s2, ofs, 64);
      }
      if ((lane & 15) == 0) {
        atomicAdd(&oS12[row], s1);
        atomicAdd(&oS12[BN_ROWS + row], s2);
      }
    }
}

// K5: LayerNorm finalize + prompt broadcast -> out
__global__ __launch_bounds__(256) void k_out(const float* __restrict__ o,
                                             const float* __restrict__ oS12,
                                             const float* __restrict__ ln_g,
                                             const float* __restrict__ ln_b,
                                             const float* __restrict__ prompt,
                                             float* __restrict__ out) {
  const int row = blockIdx.x;
  const int tid = threadIdx.x;
  float mu = oS12[row] * (1.0f / DQ);
  float va = oS12[BN_ROWS + row] * (1.0f / DQ) - mu * mu;
  float rstd = rsqrtf(va + 1e-6f);
  int b = row >> 9, n = row & 511;
  size_t obase = ((size_t)b * (NXQ * (PQ + 1)) + (size_t)n * (PQ + 1)) * DQ;
#pragma unroll
  for (int j = 0; j < 3; ++j) {
    int col = tid + j * 256;
    out[obase + col] = (o[(size_t)row * DQ + col] - mu) * rstd * ln_g[col] + ln_b[col];
  }
#pragma unroll
  for (int pi = 0; pi < PQ; ++pi)
#pragma unroll
    for (int j = 0; j < 3; ++j) {
      int col = tid + j * 256;
      out[obase + (size_t)(1 + pi) * DQ + col] = prompt[pi * DQ + col];
    }
}

extern "C" void kernel_launch(void* const* d_in, const int* in_sizes, int n_in,
                              void* d_out, int out_size, void* d_ws, size_t ws_size,
                              hipStream_t stream) {
  (void)in_sizes; (void)n_in; (void)out_size; (void)ws_size;
  const float* x    = (const float*)d_in[0];
  const float* y    = (const float*)d_in[1];
  const float* Wx   = (const float*)d_in[2];
  const float* bx   = (const float*)d_in[3];
  const float* Wy   = (const float*)d_in[4];
  const float* by   = (const float*)d_in[5];
  const float* prom = (const float*)d_in[6];
  const float* Wq   = (const float*)d_in[7];
  const float* bq   = (const float*)d_in[8];
  const float* Wk   = (const float*)d_in[9];
  const float* bk   = (const float*)d_in[10];
  const float* Wv   = (const float*)d_in[11];
  const float* bv   = (const float*)d_in[12];
  const float* Wo   = (const float*)d_in[13];
  const float* bo   = (const float*)d_in[14];
  const float* lng  = (const float*)d_in[15];
  const float* lnb  = (const float*)d_in[16];
  float* out = (float*)d_out;
  char* ws = (char*)d_ws;

  // ---- workspace layout (aliased) ----
  size_t oWyT = 0;
  size_t oWvT = oWyT + (size_t)DQ * DYQ * 2;
  size_t oWoT = oWvT + (size_t)DQ * DQ * 2;
  size_t oXw  = oWoT + (size_t)DQ * DQ * 2;
  size_t oQ   = oXw + (size_t)BQ * DQ * 4 + 256;
  size_t oQK  = oQ + (size_t)BQ * DQ * 4;
  size_t oC   = oQK + (size_t)BQ * HQ * DQ * 4;
  size_t oRq  = oC + 1024;
  size_t oS   = oRq + (size_t)MY * 4;
  size_t oYbf = oS + (size_t)2 * BN_ROWS * 4;
  size_t oZ   = oYbf + (size_t)MY * DYQ * 2;
  size_t oP   = oYbf;                                 // alias (ybf dead)
  size_t oCtx = oYbf + (size_t)BN_ROWS * HQ * DQ * 2;
  size_t oO   = oZ;                                   // alias (z dead)

  ushort_t* WyT = (ushort_t*)(ws + oWyT);
  ushort_t* WvT = (ushort_t*)(ws + oWvT);
  ushort_t* WoT = (ushort_t*)(ws + oWoT);
  float* xw  = (float*)(ws + oXw);
  float* qv  = (float*)(ws + oQ);
  float* qk  = (float*)(ws + oQK);
  float* cQ  = (float*)(ws + oC);
  float* rowsq = (float*)(ws + oRq);
  float* oS12  = (float*)(ws + oS);
  ushort_t* ybf  = (ushort_t*)(ws + oYbf);
  ushort_t* zbuf = (ushort_t*)(ws + oZ);
  ushort_t* p    = (ushort_t*)(ws + oP);
  ushort_t* ctx  = (ushort_t*)(ws + oCtx);
  float* obuf    = (float*)(ws + oO);

  k_conv<<<dim3(4096), dim3(256), 0, stream>>>(y, Wy, Wv, Wo, ybf, WyT, WvT, WoT,
                                               rowsq, oS12, xw);
  k_q1<<<dim3(BQ, 6, 8), dim3(128), 0, stream>>>(x, Wx, bx, xw);
  k_q2<<<dim3(BQ, 6), dim3(128), 0, stream>>>(xw, Wq, bq, qv);
  k_q3<<<dim3(BQ * HQ), dim3(256), 0, stream>>>(Wk, bk, qv, qk, cQ);
  k_gemm_yp<<<dim3(1536), dim3(512), 0, stream>>>(ybf, WyT, by, zbuf, rowsq);
  k_attn<<<dim3(BN_ROWS), dim3(256), 0, stream>>>(zbuf, rowsq, qk, cQ, p);
  k_gemm_pv<<<dim3(BN_ROWS / 128, HQ), dim3(256), 0, stream>>>(p, WvT, bv, ctx);
  k_gemm_o<<<dim3(BN_ROWS / 128, DQ / 64), dim3(256), 0, stream>>>(ctx, WoT, bo, obuf, oS12);
  k_out<<<dim3(BN_ROWS), dim3(256), 0, stream>>>(obuf, oS12, lng, lnb, prom, out);
}

// Round 6
// 450.690 us; speedup vs baseline: 1.4703x; 1.0459x over previous
//
#include <hip/hip_runtime.h>
#include <stdint.h>

// Problem constants
#define BQ 8
#define NXQ 512
#define WQ 16
#define DXQ 1536
#define DYQ 1024
#define DQ 768
#define HQ 12
#define PQ 8
// derived
#define MY 65536            // B*NX*W rows of y
#define BN_ROWS 4096        // B*NX

typedef __attribute__((ext_vector_type(8))) short short8;
typedef __attribute__((ext_vector_type(4))) float f32x4;
typedef unsigned short ushort_t;
typedef unsigned int uint_t;

__device__ __forceinline__ ushort_t f2bf(float f) {
  uint_t u = __float_as_uint(f);
  u += 0x7FFFu + ((u >> 16) & 1u);   // RNE
  return (ushort_t)(u >> 16);
}
__device__ __forceinline__ float bf2f(ushort_t h) {
  return __uint_as_float(((uint_t)h) << 16);
}
__device__ __forceinline__ void gload_lds16(const void* g, void* l) {
  __builtin_amdgcn_global_load_lds(
      (__attribute__((address_space(1))) unsigned int*)(g),
      (__attribute__((address_space(3))) unsigned int*)(l), 16, 0, 0);
}

// ---------------- K0: y->bf16, weight transposes, zero accumulators -----
__global__ void k_conv(const float* __restrict__ y, const float* __restrict__ Wy,
                       const float* __restrict__ Wv, const float* __restrict__ Wo,
                       ushort_t* __restrict__ ybf, ushort_t* __restrict__ WyT,
                       ushort_t* __restrict__ WvT, ushort_t* __restrict__ WoT,
                       float* __restrict__ rowsq, float* __restrict__ oS12,
                       float* __restrict__ xw) {
  const int gstride = gridDim.x * blockDim.x;
  const int g0 = blockIdx.x * blockDim.x + threadIdx.x;
  // y fp32 -> bf16
  const int NY8 = MY * DYQ / 8;
  for (int i = g0; i < NY8; i += gstride) {
    const float4* s = (const float4*)(y + (size_t)i * 8);
    float4 f0 = s[0], f1 = s[1];
    short8 hv;
    hv[0] = (short)f2bf(f0.x); hv[1] = (short)f2bf(f0.y);
    hv[2] = (short)f2bf(f0.z); hv[3] = (short)f2bf(f0.w);
    hv[4] = (short)f2bf(f1.x); hv[5] = (short)f2bf(f1.y);
    hv[6] = (short)f2bf(f1.z); hv[7] = (short)f2bf(f1.w);
    *(short8*)(ybf + (size_t)i * 8) = hv;
  }
  // zeros
  for (int i = g0; i < MY; i += gstride) rowsq[i] = 0.f;
  for (int i = g0; i < 2 * BN_ROWS; i += gstride) oS12[i] = 0.f;
  for (int i = g0; i < BQ * DQ; i += gstride) xw[i] = 0.f;
  // weight transposes (bf16)
  const int N1 = DQ * DYQ;
  const int N2 = DQ * DQ;
  const int total = N1 + 2 * N2;
  for (int i = g0; i < total; i += gstride) {
    if (i < N1) {
      int n = i / DYQ, k = i - n * DYQ;
      WyT[i] = f2bf(Wy[k * DQ + n]);
    } else if (i < N1 + N2) {
      int j = i - N1;
      int n = j / DQ, k = j - n * DQ;
      WvT[j] = f2bf(Wv[k * DQ + n]);
    } else {
      int j = i - N1 - N2;
      int n = j / DQ, k = j - n * DQ;
      WoT[j] = f2bf(Wo[k * DQ + n]);
    }
  }
}

// ---------------- q-chain ------------------------------------------------
__global__ __launch_bounds__(128) void k_q1(const float* __restrict__ x,
                                            const float* __restrict__ Wx,
                                            const float* __restrict__ bx,
                                            float* __restrict__ xw) {
  const int b = blockIdx.x, c = blockIdx.y * 128 + threadIdx.x;
  const int kc = blockIdx.z;
  const float* xr = x + (size_t)b * NXQ * DXQ + kc * 192;
  const float* wp = Wx + (size_t)kc * 192 * DQ + c;
  float acc = (kc == 0) ? bx[c] : 0.f;
  for (int k = 0; k < 192; ++k) acc += xr[k] * wp[(size_t)k * DQ];
  atomicAdd(&xw[b * DQ + c], acc);
}

__global__ __launch_bounds__(128) void k_q2(const float* __restrict__ xw,
                                            const float* __restrict__ Wq,
                                            const float* __restrict__ bq,
                                            float* __restrict__ qv) {
  const int b = blockIdx.x, c = blockIdx.y * 128 + threadIdx.x;
  const float* xr = xw + b * DQ;
  float acc = 0.f, ss = 0.f;
  for (int k = 0; k < DQ; ++k) {
    float v = xr[k];
    acc += v * Wq[(size_t)k * DQ + c];
    ss += v * v;
  }
  const float inv = 1.0f / (sqrtf(ss) + 1e-6f);
  qv[b * DQ + c] = (acc * inv + bq[c]) * 0.125f;
}

__global__ void k_q3(const float* __restrict__ Wk, const float* __restrict__ bk,
                     const float* __restrict__ qv, float* __restrict__ qk,
                     float* __restrict__ cQ) {
  const int bh = blockIdx.x;
  const int b = bh / HQ, h = bh - b * HQ;
  const int tid = threadIdx.x;
  const float* q = qv + b * DQ + h * 64;
#pragma unroll
  for (int j = 0; j < 3; ++j) {
    int dd = tid + j * 256;
    float acc = 0.f;
    for (int j2 = 0; j2 < 64; ++j2) acc += Wk[(size_t)dd * DQ + h * 64 + j2] * q[j2];
    qk[(size_t)bh * DQ + dd] = acc;
  }
  if (tid == 0) {
    float acc = 0.f;
    for (int j2 = 0; j2 < 64; ++j2) acc += q[j2] * bk[h * 64 + j2];
    cQ[bh] = acc;
  }
}

// ---------------- K1: z = ybf @ WyT^T + by (bf16), rowsq += ssq ---------
// m201-style: BM=256, BN=256, BK=64, 8 waves (2Mx4N, wave tile 128x64).
// LDS: 2 buffers x 64KB; each buffer = 4 quarters {A_ks0,A_ks1,B_ks0,B_ks1}
// of 16KB (256 rows x 32k, 64B rows, 2-bit XOR chunk swizzle).
// Per phase (=ks half): vmcnt(4); s_barrier; 12 ds_reads; 4 staging gloads
// (quarter-pair of tile t+1, same ks -> 2-phase lead); lgkmcnt(0); 32 MFMA.
__global__ __launch_bounds__(512, 1) void k_gemm_yp(const ushort_t* __restrict__ ybf,
                                                    const ushort_t* __restrict__ WyT,
                                                    const float* __restrict__ by,
                                                    ushort_t* __restrict__ z,
                                                    float* __restrict__ rowsqg) {
  __shared__ __align__(16) char smem[131072 + 1024];
  float* rowsq_l = (float*)(smem + 131072);
  const int tid = threadIdx.x, lane = tid & 63, wv = tid >> 6;
  const int wvM = wv >> 2, wvN = wv & 3;
  // decode: 3 n-blocks of a panel share g mod 8 (same XCD)
  const int g = blockIdx.x;
  const int m = (g / 24) * 8 + (g & 7);
  const int n = (g >> 3) % 3;
  const int mBase = m * 256, nBase = n * 256;
  if (tid < 256) rowsq_l[tid] = 0.f;

  // staging sources: per wave, 2 gloads per 16KB quarter (A and B)
  const int sr = lane >> 2;                 // row within 16-row group
  const int sc = (lane & 3) ^ (sr & 3);     // pre-swizzled source chunk
  const ushort_t* aQ[2]; const ushort_t* bQ[2];
  int qDst[2];
#pragma unroll
  for (int j = 0; j < 2; ++j) {
    int r = wv * 32 + j * 16 + sr;
    aQ[j] = ybf + (size_t)(mBase + r) * DYQ + sc * 8;
    bQ[j] = WyT + (size_t)(nBase + r) * DYQ + sc * 8;
    qDst[j] = (wv * 32 + j * 16) * 64;
  }
  // fragment read offsets (within a ks-region); phys chunk = q ^ (row&3)
  const int q = lane >> 4;
  int aFr[8], bFr[4];
#pragma unroll
  for (int mf = 0; mf < 8; ++mf) {
    int r = wvM * 128 + mf * 16 + (lane & 15);
    aFr[mf] = r * 64 + ((q ^ (r & 3)) << 4);
  }
#pragma unroll
  for (int nf = 0; nf < 4; ++nf) {
    int r = wvN * 64 + nf * 16 + (lane & 15);
    bFr[nf] = 32768 + r * 64 + ((q ^ (r & 3)) << 4);
  }

#define YP_STAGE(bufb, tt, ks)                                                 \
  {                                                                            \
    char* db = smem + (bufb) * 65536 + (ks) * 16384;                           \
    _Pragma("unroll") for (int j = 0; j < 2; ++j)                              \
        gload_lds16(aQ[j] + (tt) * 64 + (ks) * 32, db + qDst[j]);              \
    _Pragma("unroll") for (int j = 0; j < 2; ++j)                              \
        gload_lds16(bQ[j] + (tt) * 64 + (ks) * 32, db + 32768 + qDst[j]);      \
  }

  f32x4 acc[8][4] = {};
  YP_STAGE(0, 0, 0);
  YP_STAGE(0, 0, 1);
  for (int t = 0; t < 16; ++t) {
    const int c = t & 1;
    const char* cb = smem + c * 65536;
#pragma unroll
    for (int ks = 0; ks < 2; ++ks) {
      if (t == 15 && ks == 1) {
        asm volatile("s_waitcnt vmcnt(0)" ::: "memory");
      } else {
        asm volatile("s_waitcnt vmcnt(4)" ::: "memory");
      }
      __builtin_amdgcn_s_barrier();
      __builtin_amdgcn_sched_barrier(0);
      short8 af[8], bf[4];
#pragma unroll
      for (int mf = 0; mf < 8; ++mf)
        af[mf] = *(const short8*)(cb + ks * 16384 + aFr[mf]);
#pragma unroll
      for (int nf = 0; nf < 4; ++nf)
        bf[nf] = *(const short8*)(cb + ks * 16384 + bFr[nf]);
      if (t < 15) YP_STAGE(c ^ 1, t + 1, ks);
      asm volatile("s_waitcnt lgkmcnt(0)" ::: "memory");
      __builtin_amdgcn_sched_barrier(0);
      __builtin_amdgcn_s_setprio(1);
#pragma unroll
      for (int nf = 0; nf < 4; ++nf)
#pragma unroll
        for (int mf = 0; mf < 8; ++mf)
          acc[mf][nf] = __builtin_amdgcn_mfma_f32_16x16x32_bf16(af[mf], bf[nf],
                                                                acc[mf][nf], 0, 0, 0);
      __builtin_amdgcn_s_setprio(0);
      __builtin_amdgcn_sched_barrier(0);
    }
  }
  __syncthreads();

  // ---- epilogue: +bias, z tile (256x256) -> LDS, row ssq partials ----
  float byv[4];
#pragma unroll
  for (int nf = 0; nf < 4; ++nf) byv[nf] = by[nBase + wvN * 64 + nf * 16 + (lane & 15)];
#pragma unroll
  for (int mf = 0; mf < 8; ++mf) {
#pragma unroll
    for (int rr = 0; rr < 4; ++rr) {
      int row_l = wvM * 128 + mf * 16 + (lane >> 4) * 4 + rr;
      float ss = 0.f;
#pragma unroll
      for (int nf = 0; nf < 4; ++nf) {
        float zv = acc[mf][nf][rr] + byv[nf];
        ss += zv * zv;
        int col_l = wvN * 64 + nf * 16 + (lane & 15);
        *(ushort_t*)(smem + row_l * 512 + col_l * 2) = f2bf(zv);
      }
#pragma unroll
      for (int o = 1; o < 16; o <<= 1) ss += __shfl_xor(ss, o, 64);
      if ((lane & 15) == 0) atomicAdd(&rowsq_l[row_l], ss);
    }
  }
  __syncthreads();
  if (tid < 256) atomicAdd(&rowsqg[mBase + tid], rowsq_l[tid]);
#pragma unroll
  for (int it = 0; it < 16; ++it) {
    int row = it * 16 + (tid >> 5);
    int ch = tid & 31;
    uint4 v = *(const uint4*)(smem + row * 512 + ch * 16);
    *(uint4*)(z + (size_t)(mBase + row) * DQ + nBase + ch * 8) = v;
  }
}

// ---------------- K2: windowed attention -> p[b,n,h,:] ------------------
__global__ __launch_bounds__(256) void k_attn(const ushort_t* __restrict__ z,
                                              const float* __restrict__ rowsqg,
                                              const float* __restrict__ qk,
                                              const float* __restrict__ cQ,
                                              ushort_t* __restrict__ p) {
  __shared__ __align__(16) char smem[16 * 1552 + 192 * 4 * 2 + 64];
  float* s_l = (float*)(smem + 16 * 1552);
  float* a_l = s_l + 192;
  float* inv_l = a_l + 192;
  const int bn = blockIdx.x, b = bn >> 9;
  const int tid = threadIdx.x;
  if (tid < 16) inv_l[tid] = 1.0f / (sqrtf(rowsqg[bn * 16 + tid]) + 1e-6f);
  for (int j = tid; j < 16 * 96; j += 256) {
    int w = j / 96, ch = j - w * 96;
    *(short8*)(smem + w * 1552 + ch * 16) =
        *(const short8*)(z + ((size_t)bn * 16 + w) * DQ + ch * 8);
  }
  __syncthreads();
  if (tid < 192) {  // (h,w): s = (z_w . qk~) * inv_w + cQ
    int h = tid >> 4, w = tid & 15;
    const float4* qkp = (const float4*)(qk + (size_t)(b * HQ + h) * DQ);
    float acc = 0.f;
    const char* yrow = smem + w * 1552;
    for (int dc = 0; dc < 192; ++dc) {
      float4 q4 = qkp[dc];
      uint2 hh = *(const uint2*)(yrow + dc * 8);
      acc += q4.x * bf2f((ushort_t)(hh.x & 0xffff));
      acc += q4.y * bf2f((ushort_t)(hh.x >> 16));
      acc += q4.z * bf2f((ushort_t)(hh.y & 0xffff));
      acc += q4.w * bf2f((ushort_t)(hh.y >> 16));
    }
    s_l[tid] = acc * inv_l[w] + cQ[b * HQ + h];
  }
  __syncthreads();
  if (tid < 12) {  // softmax over w; fold inv_w into weights
    float mx = -1e30f;
#pragma unroll
    for (int w = 0; w < 16; ++w) mx = fmaxf(mx, s_l[tid * 16 + w]);
    float sm = 0.f, ev[16];
#pragma unroll
    for (int w = 0; w < 16; ++w) {
      ev[w] = __expf(s_l[tid * 16 + w] - mx);
      sm += ev[w];
    }
    float rden = 1.0f / sm;
#pragma unroll
    for (int w = 0; w < 16; ++w) a_l[tid * 16 + w] = ev[w] * rden * inv_l[w];
  }
  __syncthreads();
  float zr[16][3];
#pragma unroll
  for (int w = 0; w < 16; ++w)
#pragma unroll
    for (int i = 0; i < 3; ++i)
      zr[w][i] = bf2f(*(const ushort_t*)(smem + w * 1552 + (tid + i * 256) * 2));
  for (int h = 0; h < HQ; ++h) {
    float acc0 = 0.f, acc1 = 0.f, acc2 = 0.f;
#pragma unroll
    for (int w = 0; w < 16; ++w) {
      float aw = a_l[h * 16 + w];
      acc0 += aw * zr[w][0];
      acc1 += aw * zr[w][1];
      acc2 += aw * zr[w][2];
    }
    size_t base = ((size_t)bn * HQ + h) * DQ + tid;
    p[base] = f2bf(acc0);
    p[base + 256] = f2bf(acc1);
    p[base + 512] = f2bf(acc2);
  }
}

// ---------------- K3: ctx[:, h*64:(h+1)*64] = p_h @ Wv_h + bv -----------
#define PV_TSZ 24576         // A 16KB + B 8KB
__global__ __launch_bounds__(256) void k_gemm_pv(const ushort_t* __restrict__ p,
                                                 const ushort_t* __restrict__ WvT,
                                                 const float* __restrict__ bv,
                                                 ushort_t* __restrict__ ctx) {
  __shared__ __align__(16) char smem[3 * PV_TSZ];
  const int tid = threadIdx.x, lane = tid & 63, wv = tid >> 6;
  const int wvM = wv >> 1, wvN = wv & 1;
  const int mBase = blockIdx.x * 128, h = blockIdx.y;
  const int l8 = lane >> 3;
  const int c8 = (lane & 7) ^ (l8 & 7);
  const ushort_t* aSrc[4]; const ushort_t* bSrc[2];
  int aDst[4], bDst[2];
#pragma unroll
  for (int j = 0; j < 4; ++j) {
    int r = wv * 32 + j * 8 + l8;
    aSrc[j] = p + ((size_t)(mBase + r) * HQ + h) * DQ + c8 * 8;
    aDst[j] = (wv * 32 + j * 8) * 128;
  }
#pragma unroll
  for (int j = 0; j < 2; ++j) {
    int r = wv * 16 + j * 8 + l8;
    bSrc[j] = WvT + (size_t)(h * 64 + r) * DQ + c8 * 8;
    bDst[j] = 16384 + (wv * 16 + j * 8) * 128;
  }
  const int q = lane >> 4;
  int aRowB[4], aSw[4], bRowB[2], bSw[2];
#pragma unroll
  for (int mf = 0; mf < 4; ++mf) {
    int r = wvM * 64 + mf * 16 + (lane & 15);
    aRowB[mf] = r * 128; aSw[mf] = r & 7;
  }
#pragma unroll
  for (int nf = 0; nf < 2; ++nf) {
    int r = wvN * 32 + nf * 16 + (lane & 15);
    bRowB[nf] = 16384 + r * 128; bSw[nf] = r & 7;
  }
#define PV_STAGE(dbuf, t)                                                      \
  {                                                                            \
    char* db = smem + (dbuf) * PV_TSZ;                                         \
    _Pragma("unroll") for (int j = 0; j < 4; ++j)                              \
        gload_lds16(aSrc[j] + (t) * 64, db + aDst[j]);                         \
    _Pragma("unroll") for (int j = 0; j < 2; ++j)                              \
        gload_lds16(bSrc[j] + (t) * 64, db + bDst[j]);                         \
  }
  f32x4 acc[4][2] = {};
  PV_STAGE(0, 0);
  PV_STAGE(1, 1);
  int bR = 0, bS = 2;
  for (int t = 0; t < 12; ++t) {
    if (t < 11) {
      asm volatile("s_waitcnt vmcnt(6)" ::: "memory");
    } else {
      asm volatile("s_waitcnt vmcnt(0)" ::: "memory");
    }
    __builtin_amdgcn_s_barrier();
    __builtin_amdgcn_sched_barrier(0);
    if (t + 2 < 12) PV_STAGE(bS, t + 2);
    const char* cur = smem + bR * PV_TSZ;
#pragma unroll
    for (int ks = 0; ks < 2; ++ks) {
      short8 af[4], bf[2];
#pragma unroll
      for (int mf = 0; mf < 4; ++mf)
        af[mf] = *(const short8*)(cur + aRowB[mf] + (((ks * 4 + q) ^ aSw[mf]) << 4));
#pragma unroll
      for (int nf = 0; nf < 2; ++nf)
        bf[nf] = *(const short8*)(cur + bRowB[nf] + (((ks * 4 + q) ^ bSw[nf]) << 4));
#pragma unroll
      for (int nf = 0; nf < 2; ++nf)
#pragma unroll
        for (int mf = 0; mf < 4; ++mf)
          acc[mf][nf] = __builtin_amdgcn_mfma_f32_16x16x32_bf16(af[mf], bf[nf],
                                                                acc[mf][nf], 0, 0, 0);
    }
    bR = (bR == 2) ? 0 : bR + 1;
    bS = (bS == 2) ? 0 : bS + 1;
  }
#pragma unroll
  for (int nf = 0; nf < 2; ++nf) {
    int col = h * 64 + wvN * 32 + nf * 16 + (lane & 15);
    float bvv = bv[col];
#pragma unroll
    for (int mf = 0; mf < 4; ++mf)
#pragma unroll
      for (int rr = 0; rr < 4; ++rr) {
        int row = mBase + wvM * 64 + mf * 16 + (lane >> 4) * 4 + rr;
        ctx[(size_t)row * DQ + col] = f2bf(acc[mf][nf][rr] + bvv);
      }
  }
}

// ---------------- K4: o = ctx @ Wo + bo (fp32) + row s1/s2 atomics ------
__global__ __launch_bounds__(256) void k_gemm_o(const ushort_t* __restrict__ ctx,
                                                const ushort_t* __restrict__ WoT,
                                                const float* __restrict__ bo,
                                                float* __restrict__ o,
                                                float* __restrict__ oS12) {
  __shared__ __align__(16) char smem[3 * PV_TSZ];
  const int tid = threadIdx.x, lane = tid & 63, wv = tid >> 6;
  const int wvM = wv >> 1, wvN = wv & 1;
  const int mBase = blockIdx.x * 128, nBase = blockIdx.y * 64;
  const int l8 = lane >> 3;
  const int c8 = (lane & 7) ^ (l8 & 7);
  const ushort_t* aSrc[4]; const ushort_t* bSrc[2];
  int aDst[4], bDst[2];
#pragma unroll
  for (int j = 0; j < 4; ++j) {
    int r = wv * 32 + j * 8 + l8;
    aSrc[j] = ctx + (size_t)(mBase + r) * DQ + c8 * 8;
    aDst[j] = (wv * 32 + j * 8) * 128;
  }
#pragma unroll
  for (int j = 0; j < 2; ++j) {
    int r = wv * 16 + j * 8 + l8;
    bSrc[j] = WoT + (size_t)(nBase + r) * DQ + c8 * 8;
    bDst[j] = 16384 + (wv * 16 + j * 8) * 128;
  }
  const int q = lane >> 4;
  int aRowB[4], aSw[4], bRowB[2], bSw[2];
#pragma unroll
  for (int mf = 0; mf < 4; ++mf) {
    int r = wvM * 64 + mf * 16 + (lane & 15);
    aRowB[mf] = r * 128; aSw[mf] = r & 7;
  }
#pragma unroll
  for (int nf = 0; nf < 2; ++nf) {
    int r = wvN * 32 + nf * 16 + (lane & 15);
    bRowB[nf] = 16384 + r * 128; bSw[nf] = r & 7;
  }
  f32x4 acc[4][2] = {};
#define O_STAGE(dbuf, t)                                                       \
  {                                                                            \
    char* db = smem + (dbuf) * PV_TSZ;                                         \
    _Pragma("unroll") for (int j = 0; j < 4; ++j)                              \
        gload_lds16(aSrc[j] + (t) * 64, db + aDst[j]);                         \
    _Pragma("unroll") for (int j = 0; j < 2; ++j)                              \
        gload_lds16(bSrc[j] + (t) * 64, db + bDst[j]);                         \
  }
  O_STAGE(0, 0);
  O_STAGE(1, 1);
  int bR = 0, bS = 2;
  for (int t = 0; t < 12; ++t) {
    if (t < 11) {
      asm volatile("s_waitcnt vmcnt(6)" ::: "memory");
    } else {
      asm volatile("s_waitcnt vmcnt(0)" ::: "memory");
    }
    __builtin_amdgcn_s_barrier();
    __builtin_amdgcn_sched_barrier(0);
    if (t + 2 < 12) O_STAGE(bS, t + 2);
    const char* cur = smem + bR * PV_TSZ;
#pragma unroll
    for (int ks = 0; ks < 2; ++ks) {
      short8 af[4], bf[2];
#pragma unroll
      for (int mf = 0; mf < 4; ++mf)
        af[mf] = *(const short8*)(cur + aRowB[mf] + (((ks * 4 + q) ^ aSw[mf]) << 4));
#pragma unroll
      for (int nf = 0; nf < 2; ++nf)
        bf[nf] = *(const short8*)(cur + bRowB[nf] + (((ks * 4 + q) ^ bSw[nf]) << 4));
#pragma unroll
      for (int nf = 0; nf < 2; ++nf)
#pragma unroll
        for (int mf = 0; mf < 4; ++mf)
          acc[mf][nf] = __builtin_amdgcn_mfma_f32_16x16x32_bf16(af[mf], bf[nf],
                                                                acc[mf][nf], 0, 0, 0);
    }
    bR = (bR == 2) ? 0 : bR + 1;
    bS = (bS == 2) ? 0 : bS + 1;
  }
  float bo0 = bo[nBase + wvN * 32 + (lane & 15)];
  float bo1 = bo[nBase + wvN * 32 + 16 + (lane & 15)];
#pragma unroll
  for (int mf = 0; mf < 4; ++mf)
#pragma unroll
    for (int rr = 0; rr < 4; ++rr) {
      int row = mBase + wvM * 64 + mf * 16 + (lane >> 4) * 4 + rr;
      float z0 = acc[mf][0][rr] + bo0;
      float z1 = acc[mf][1][rr] + bo1;
      o[(size_t)row * DQ + nBase + wvN * 32 + (lane & 15)] = z0;
      o[(size_t)row * DQ + nBase + wvN * 32 + 16 + (lane & 15)] = z1;
      float s1 = z0 + z1, s2 = z0 * z0 + z1 * z1;
#pragma unroll
      for (int ofs = 1; ofs < 16; ofs <<= 1) {
        s1 += __shfl_xor(s1, ofs, 64);
        s2 += __shfl_xor(s2, ofs, 64);
      }
      if ((lane & 15) == 0) {
        atomicAdd(&oS12[row], s1);
        atomicAdd(&oS12[BN_ROWS + row], s2);
      }
    }
}

// K5: LayerNorm finalize + prompt broadcast -> out
__global__ __launch_bounds__(256) void k_out(const float* __restrict__ o,
                                             const float* __restrict__ oS12,
                                             const float* __restrict__ ln_g,
                                             const float* __restrict__ ln_b,
                                             const float* __restrict__ prompt,
                                             float* __restrict__ out) {
  const int row = blockIdx.x;
  const int tid = threadIdx.x;
  float mu = oS12[row] * (1.0f / DQ);
  float va = oS12[BN_ROWS + row] * (1.0f / DQ) - mu * mu;
  float rstd = rsqrtf(va + 1e-6f);
  int b = row >> 9, n = row & 511;
  size_t obase = ((size_t)b * (NXQ * (PQ + 1)) + (size_t)n * (PQ + 1)) * DQ;
#pragma unroll
  for (int j = 0; j < 3; ++j) {
    int col = tid + j * 256;
    out[obase + col] = (o[(size_t)row * DQ + col] - mu) * rstd * ln_g[col] + ln_b[col];
  }
#pragma unroll
  for (int pi = 0; pi < PQ; ++pi)
#pragma unroll
    for (int j = 0; j < 3; ++j) {
      int col = tid + j * 256;
      out[obase + (size_t)(1 + pi) * DQ + col] = prompt[pi * DQ + col];
    }
}

extern "C" void kernel_launch(void* const* d_in, const int* in_sizes, int n_in,
                              void* d_out, int out_size, void* d_ws, size_t ws_size,
                              hipStream_t stream) {
  (void)in_sizes; (void)n_in; (void)out_size; (void)ws_size;
  const float* x    = (const float*)d_in[0];
  const float* y    = (const float*)d_in[1];
  const float* Wx   = (const float*)d_in[2];
  const float* bx   = (const float*)d_in[3];
  const float* Wy   = (const float*)d_in[4];
  const float* by   = (const float*)d_in[5];
  const float* prom = (const float*)d_in[6];
  const float* Wq   = (const float*)d_in[7];
  const float* bq   = (const float*)d_in[8];
  const float* Wk   = (const float*)d_in[9];
  const float* bk   = (const float*)d_in[10];
  const float* Wv   = (const float*)d_in[11];
  const float* bv   = (const float*)d_in[12];
  const float* Wo   = (const float*)d_in[13];
  const float* bo   = (const float*)d_in[14];
  const float* lng  = (const float*)d_in[15];
  const float* lnb  = (const float*)d_in[16];
  float* out = (float*)d_out;
  char* ws = (char*)d_ws;

  // ---- workspace layout (aliased) ----
  size_t oWyT = 0;
  size_t oWvT = oWyT + (size_t)DQ * DYQ * 2;
  size_t oWoT = oWvT + (size_t)DQ * DQ * 2;
  size_t oXw  = oWoT + (size_t)DQ * DQ * 2;
  size_t oQ   = oXw + (size_t)BQ * DQ * 4 + 256;
  size_t oQK  = oQ + (size_t)BQ * DQ * 4;
  size_t oC   = oQK + (size_t)BQ * HQ * DQ * 4;
  size_t oRq  = oC + 1024;
  size_t oS   = oRq + (size_t)MY * 4;
  size_t oYbf = oS + (size_t)2 * BN_ROWS * 4;
  size_t oZ   = oYbf + (size_t)MY * DYQ * 2;
  size_t oP   = oYbf;                                 // alias (ybf dead)
  size_t oCtx = oYbf + (size_t)BN_ROWS * HQ * DQ * 2;
  size_t oO   = oZ;                                   // alias (z dead)

  ushort_t* WyT = (ushort_t*)(ws + oWyT);
  ushort_t* WvT = (ushort_t*)(ws + oWvT);
  ushort_t* WoT = (ushort_t*)(ws + oWoT);
  float* xw  = (float*)(ws + oXw);
  float* qv  = (float*)(ws + oQ);
  float* qk  = (float*)(ws + oQK);
  float* cQ  = (float*)(ws + oC);
  float* rowsq = (float*)(ws + oRq);
  float* oS12  = (float*)(ws + oS);
  ushort_t* ybf  = (ushort_t*)(ws + oYbf);
  ushort_t* zbuf = (ushort_t*)(ws + oZ);
  ushort_t* p    = (ushort_t*)(ws + oP);
  ushort_t* ctx  = (ushort_t*)(ws + oCtx);
  float* obuf    = (float*)(ws + oO);

  k_conv<<<dim3(4096), dim3(256), 0, stream>>>(y, Wy, Wv, Wo, ybf, WyT, WvT, WoT,
                                               rowsq, oS12, xw);
  k_q1<<<dim3(BQ, 6, 8), dim3(128), 0, stream>>>(x, Wx, bx, xw);
  k_q2<<<dim3(BQ, 6), dim3(128), 0, stream>>>(xw, Wq, bq, qv);
  k_q3<<<dim3(BQ * HQ), dim3(256), 0, stream>>>(Wk, bk, qv, qk, cQ);
  k_gemm_yp<<<dim3(768), dim3(512), 0, stream>>>(ybf, WyT, by, zbuf, rowsq);
  k_attn<<<dim3(BN_ROWS), dim3(256), 0, stream>>>(zbuf, rowsq, qk, cQ, p);
  k_gemm_pv<<<dim3(BN_ROWS / 128, HQ), dim3(256), 0, stream>>>(p, WvT, bv, ctx);
  k_gemm_o<<<dim3(BN_ROWS / 128, DQ / 64), dim3(256), 0, stream>>>(ctx, WoT, bo, obuf, oS12);
  k_out<<<dim3(BN_ROWS), dim3(256), 0, stream>>>(obuf, oS12, lng, lnb, prom, out);
}